// Round 6
// baseline (364.582 us; speedup 1.0000x reference)
//
#include <hip/hip_runtime.h>
#include <hip/hip_bf16.h>

#define T_ 4
#define C_ 64
#define H_ 128
#define W_ 128
#define CI_ 16
#define PS_ 7
#define NC_ 729       // 27*27 candidates per query
#define S0_ 4
#define KS_ 100
#define NQ_ 1024      // 32*32 queries per frame
#define SCALE_ 10.0f
#define HW_ (H_*W_)
#define RW_ 45        // 4x4-tile region dim (float4); 45%8=5 -> bank rotation
#define LCAP_ 768
#define CB_ 8         // conv3x3 channel batch (24 dwordx4 in flight)

typedef float v2f __attribute__((ext_vector_type(2)));
#if __has_builtin(__builtin_elementwise_fma)
#define VFMA(a, b, c) __builtin_elementwise_fma((a), (b), (c))
#else
#define VFMA(a, b, c) ((a) * (b) + (c))
#endif

// ---------------- conv 3x3, 64->16, BRANCH-FREE batched loads ---------------
__device__ __forceinline__ float4 colfix(float4 r, bool loB, bool hiB) {
  float4 o;
  o.x = loB ? 0.f : (hiB ? r.y : r.x);
  o.y = loB ? r.x : (hiB ? r.z : r.y);
  o.z = loB ? r.y : (hiB ? r.w : r.z);
  o.w = loB ? r.z : (hiB ? 0.f : r.w);
  return o;
}

__global__ __launch_bounds__(128, 1) void conv3x3_kernel(
    const float* __restrict__ vid, const float* __restrict__ gw,
    const float* __restrict__ gb, float4* __restrict__ v1cs) {
  __shared__ float wls[C_ * 9 * 4];   // [c][k][co]
  const int tid = threadIdx.x;
  const int g = blockIdx.y, t = blockIdx.z;
  for (int m = tid; m < C_ * 9 * 4; m += 128) {
    int co = m & 3, ck = m >> 2;
    wls[m] = gw[((size_t)(g * 4 + co) * C_) * 9 + ck];
  }
  __syncthreads();
  const int ti0 = (blockIdx.x >> 3) * 16, tj0 = (blockIdx.x & 7) * 16;
  const int u = tid >> 3, v = tid & 7;   // 16 rows x 8 col-pairs
  const int i = ti0 + u, j0 = tj0 + 2 * v;
  const int c0 = j0 - 1;
  const int c0c = min(max(c0, 0), W_ - 4);
  const bool loB = (c0 < 0), hiB = (c0 > W_ - 4);
  const int rm1 = max(i - 1, 0), rp1 = min(i + 1, H_ - 1);
  const float mk0 = (i > 0) ? 1.f : 0.f;
  const float mk2 = (i < H_ - 1) ? 1.f : 0.f;
  const int o0 = rm1 * W_ + c0c, o1 = i * W_ + c0c, o2 = rp1 * W_ + c0c;

  float accA[4], accB[4];
#pragma unroll
  for (int co = 0; co < 4; ++co) { accA[co] = gb[g * 4 + co]; accB[co] = gb[g * 4 + co]; }

  const float* vb = vid + ((size_t)t * C_) * HW_;
#pragma unroll 1
  for (int cb = 0; cb < C_; cb += CB_) {
    float4 r[CB_][3];
#pragma unroll
    for (int c = 0; c < CB_; ++c) {       // 24 UNCONDITIONAL loads -> in flight
      const float* p = vb + (size_t)(cb + c) * HW_;
      r[c][0] = *(const float4*)(p + o0);
      r[c][1] = *(const float4*)(p + o1);
      r[c][2] = *(const float4*)(p + o2);
    }
#pragma unroll
    for (int c = 0; c < CB_; ++c) {
      float4 f0 = colfix(r[c][0], loB, hiB);
      float4 f1 = colfix(r[c][1], loB, hiB);
      float4 f2 = colfix(r[c][2], loB, hiB);
      f0.x *= mk0; f0.y *= mk0; f0.z *= mk0; f0.w *= mk0;
      f2.x *= mk2; f2.y *= mk2; f2.z *= mk2; f2.w *= mk2;
      const float* wc = &wls[(cb + c) * 36];
      float e0[4] = {f0.x, f0.y, f0.z, f0.w};
      float e1[4] = {f1.x, f1.y, f1.z, f1.w};
      float e2[4] = {f2.x, f2.y, f2.z, f2.w};
#pragma unroll
      for (int kj = 0; kj < 3; ++kj) {
#pragma unroll
        for (int co = 0; co < 4; ++co) {
          accA[co] = fmaf(wc[(0 * 3 + kj) * 4 + co], e0[kj],     accA[co]);
          accB[co] = fmaf(wc[(0 * 3 + kj) * 4 + co], e0[kj + 1], accB[co]);
          accA[co] = fmaf(wc[(1 * 3 + kj) * 4 + co], e1[kj],     accA[co]);
          accB[co] = fmaf(wc[(1 * 3 + kj) * 4 + co], e1[kj + 1], accB[co]);
          accA[co] = fmaf(wc[(2 * 3 + kj) * 4 + co], e2[kj],     accA[co]);
          accB[co] = fmaf(wc[(2 * 3 + kj) * 4 + co], e2[kj + 1], accB[co]);
        }
      }
    }
  }
  const size_t o = ((size_t)g * T_ + t) * HW_ + i * W_ + j0;
  v1cs[o]     = make_float4(accA[0], accA[1], accA[2], accA[3]);
  v1cs[o + 1] = make_float4(accB[0], accB[1], accB[2], accB[3]);
}

// ---------------- conv 1x1, 64->16, chunk-major float4 output ----------------
__global__ __launch_bounds__(256, 1) void conv1x1_kernel(
    const float* __restrict__ vid, const float* __restrict__ tw,
    const float* __restrict__ tb, float4* __restrict__ v2cs) {
  __shared__ float w[C_ * 4];
  const int t = blockIdx.y, cc = blockIdx.z;
  for (int m = threadIdx.x; m < C_ * 4; m += 256) {
    int o = m & 3, c = m >> 2;
    w[m] = tw[(cc * 4 + o) * C_ + c];
  }
  __syncthreads();
  const int pix = blockIdx.x * 256 + threadIdx.x;
  float acc[4];
#pragma unroll
  for (int o = 0; o < 4; ++o) acc[o] = tb[cc * 4 + o];
  const float* vb = vid + ((size_t)t * C_) * HW_ + pix;
#pragma unroll 1
  for (int c0 = 0; c0 < C_; c0 += 16) {
    float x[16];
#pragma unroll
    for (int uu = 0; uu < 16; ++uu) x[uu] = vb[(size_t)(c0 + uu) * HW_];
#pragma unroll
    for (int uu = 0; uu < 16; ++uu)
#pragma unroll
      for (int o = 0; o < 4; ++o)
        acc[o] = fmaf(w[(c0 + uu) * 4 + o], x[uu], acc[o]);
  }
  v2cs[((size_t)cc * T_ + t) * HW_ + pix] = make_float4(acc[0], acc[1], acc[2], acc[3]);
}

// ---------------- dists: 1024-thr block = pair-trick + r-split --------------
// 16 waves co-resident (intra-block => guaranteed 4 waves/SIMD; R5 showed the
// dispatcher won't co-schedule separate blocks). Waves 0-7: pair geometry
// (16 queries, lane la in [0,30] serves q0 at a=la and q1=+4 rows at a=la-4),
// patch rows r=0..3. Waves 8-15: same queries, rows r=4..6. Partial dists go
// to distG / distB; select sums (dual). Per-CU LDS/VALU totals unchanged vs
// R3 -- only residency changes. LDS 2x2025x16B = 64.8KB (dbuf).
// Fallback (!dual): memset distG + atomicAdd both halves (bg-dup guarded).
__global__ __launch_bounds__(1024, 4) void dist_kernel(
    const float4* __restrict__ v1cs, float* __restrict__ distG,
    float* __restrict__ distB, int use_atomic) {
  __shared__ float4 Rs[2][2025];
  const int tid = threadIdx.x;
  const int t = blockIdx.y;
  const int qi0 = (blockIdx.x >> 3) * 16, qj0 = (blockIdx.x & 7) * 16;
  const int w = tid >> 6, lane = tid & 63;
  const int ws = w & 7, rset = w >> 3;           // 8 pair-configs x 2 r-sets
  const int r0 = rset ? 4 : 0, r1 = rset ? 7 : 4;
  const int pr = ws >> 2, dj = (ws & 3) * 4;     // pair-row {0,1}, col-tile
  const int rbase = 8 * pr;
  const int qi_p = qi0 + rbase;                  // q0 pixel row; q1 = qi_p+4
  const int qj = qj0 + dj;
  const int la = lane >> 1, bg = lane & 1;
  const int b_lo = max(13 - qj, 0);
  const int bs = bg ? 13 : b_lo;
  const int a_lo0 = max(13 - qi_p, 0);
  const int a_lo1 = max(9 - qi_p, 0);
  const bool compute_ok = (la < 31);
  const bool bdup = (bg == 0) && (b_lo == 13);   // qj==0: bg0 duplicates bg1

  // staging: 2 float4 per thread per chunk; clamped source, linear dest
  int soff[2];
#pragma unroll
  for (int k = 0; k < 2; ++k) {
    int p = min(tid + 1024 * k, RW_ * RW_ - 1);
    int uu = p / RW_, vv = p - uu * RW_;
    int row = min(max(qi0 - 13 + uu, 0), H_ - 1);
    int col = min(max(qj0 - 13 + vv, 0), W_ - 1);
    soff[k] = row * W_ + col;
  }
  const int d0 = tid, d1 = min(tid + 1024, RW_ * RW_ - 1);  // dup-writes benign

  v2f acc0[14], acc1[14];
#pragma unroll
  for (int j = 0; j < 14; ++j) { acc0[j] = (v2f){0.f, 0.f}; acc1[j] = (v2f){0.f, 0.f}; }

  float4 st[2];
  {
    const float4* src = v1cs + ((size_t)0 * T_ + t) * HW_;
    st[0] = src[soff[0]];
    st[1] = src[soff[1]];
  }
  int cur = 0;
#pragma unroll 1
  for (int ci = 0; ci < 4; ++ci) {
    float4* buf = &Rs[cur][0];
    buf[d0] = st[0];                              // stage chunk ci
    buf[d1] = st[1];
    if (ci < 3) {                                 // prefetch chunk ci+1
      const float4* src = v1cs + ((size_t)(ci + 1) * T_ + t) * HW_;
      st[0] = src[soff[0]];
      st[1] = src[soff[1]];
    }
    __syncthreads();                              // buf[cur] ready
    if (compute_ok) {
#pragma unroll 1
      for (int r = r0; r < r1; ++r) {
        v2f q0lo[7], q0hi[7], q1lo[7], q1hi[7];
        const float4* q0row = &buf[(rbase + 13 + r) * RW_ + dj + 13];
#pragma unroll
        for (int s = 0; s < 7; ++s) {
          float4 qq = q0row[s];                   // q0 patch row (broadcast)
          q0lo[s] = (v2f){qq.x, qq.y};
          q0hi[s] = (v2f){qq.z, qq.w};
          float4 q2 = q0row[4 * RW_ + s];         // q1 patch row = +4 rows
          q1lo[s] = (v2f){q2.x, q2.y};
          q1hi[s] = (v2f){q2.z, q2.w};
        }
        const float4* crow = &buf[(rbase + la + r) * RW_ + dj + bs];
#pragma unroll
        for (int y = 0; y < 20; ++y) {
          float4 vv4 = crow[y];                   // shared by q0 AND q1
          v2f vlo = (v2f){vv4.x, vv4.y}, vhi = (v2f){vv4.z, vv4.w};
          const int s_lo = (y > 13) ? (y - 13) : 0;
          const int s_hi = (y < 6) ? y : 6;
#pragma unroll
          for (int s = s_lo; s <= s_hi; ++s) {
            int j = y - s;
            acc0[j] = VFMA(q0lo[s], vlo, acc0[j]);
            acc0[j] = VFMA(q0hi[s], vhi, acc0[j]);
            acc1[j] = VFMA(q1lo[s], vlo, acc1[j]);
            acc1[j] = VFMA(q1hi[s], vhi, acc1[j]);
          }
        }
      }
    }
    __syncthreads();                              // all reads done before re-stage
    cur ^= 1;
  }
  if (compute_ok) {
    float* outB = (rset && !use_atomic) ? distB : distG;
    const int q0q = ((qi_p >> 2) << 5) + (qj >> 2);
    if (la >= a_lo0 && la <= 26 && !(use_atomic && bdup)) {
      float* out = outB + ((size_t)t * NQ_ + q0q) * NC_ + la * 27 + bs;
      if (use_atomic) {
#pragma unroll
        for (int j = 0; j < 14; ++j) atomicAdd(out + j, acc0[j].x + acc0[j].y);
      } else {
#pragma unroll
        for (int j = 0; j < 14; ++j) out[j] = acc0[j].x + acc0[j].y;
      }
    }
    const int a1 = la - 4;
    if (a1 >= a_lo1 && a1 <= 26 && !(use_atomic && bdup)) {
      float* out = outB + ((size_t)t * NQ_ + (q0q + 32)) * NC_ + a1 * 27 + bs;
      if (use_atomic) {
#pragma unroll
        for (int j = 0; j < 14; ++j) atomicAdd(out + j, acc1[j].x + acc1[j].y);
      } else {
#pragma unroll
        for (int j = 0; j < 14; ++j) out[j] = acc1[j].x + acc1[j].y;
      }
    }
  }
}

// ---------------- select: 2-level radix top-100, wave-primitive scans -------
__global__ __launch_bounds__(256) void select_kernel(
    const float* __restrict__ distA, const float* __restrict__ distB, int dual,
    int* __restrict__ sel_n, float* __restrict__ sel_w,
    float* __restrict__ wsum_out) {
  __shared__ float dist[NC_];
  __shared__ unsigned int ukey[NC_];
  __shared__ float redf[4];
  __shared__ unsigned int hist[256];
  __shared__ int lk[LCAP_];
  __shared__ unsigned int lkey[LCAP_];
  __shared__ unsigned int scal[6];   // 0=beta 1=run 2=cursor 3=listlen 4=beta2 5=run2

  const int tid = threadIdx.x;
  const int lane = tid & 63, wid = tid >> 6;
  const int q = blockIdx.x, t = blockIdx.y;
  const int qi = (q >> 5) * S0_, qj = (q & 31) * S0_;
  const int a_lo = max(13 - qi, 0), b_lo = max(13 - qj, 0);
  const size_t base = ((size_t)t * NQ_ + q) * NC_;

  for (int h = tid; h < 256; h += 256) hist[h] = 0;
  if (tid == 0) { scal[2] = 0; scal[3] = 0; }
  float lmax = -INFINITY;
  for (int k = tid; k < NC_; k += 256) {
    int aa = k / 27, bb = k - aa * 27;
    int kk = max(aa, a_lo) * 27 + max(bb, b_lo);
    float d = distA[base + kk];
    if (dual) d += distB[base + kk];
    dist[k] = d;
    unsigned int u = __float_as_uint(d);
    ukey[k] = u ^ (((unsigned int)((int)u >> 31)) | 0x80000000u);
    lmax = fmaxf(lmax, d);
  }
#pragma unroll
  for (int off = 32; off > 0; off >>= 1)
    lmax = fmaxf(lmax, __shfl_down(lmax, off, 64));
  if (lane == 0) redf[wid] = lmax;
  __syncthreads();                                             // B1
  const float dmax = fmaxf(fmaxf(redf[0], redf[1]), fmaxf(redf[2], redf[3]));
  for (int k = tid; k < NC_; k += 256) atomicAdd(&hist[ukey[k] >> 24], 1u);
  __syncthreads();                                             // B2
  if (wid == 0) {
    int s4 = (int)(hist[lane * 4] + hist[lane * 4 + 1] + hist[lane * 4 + 2] + hist[lane * 4 + 3]);
    int s = s4;
#pragma unroll
    for (int off = 1; off < 64; off <<= 1) {
      int o = __shfl_down(s, off, 64);
      if (lane + off < 64) s += o;
    }
    int above = s - s4;
    if (above < KS_ && s >= KS_) {
      int run = above;
#pragma unroll
      for (int bb = 3; bb >= 0; --bb) {
        int h = (int)hist[lane * 4 + bb];
        if (run + h >= KS_) { scal[0] = (unsigned int)(lane * 4 + bb); scal[1] = (unsigned int)run; break; }
        run += h;
      }
    }
  }
  __syncthreads();                                             // B3
  const unsigned int beta = scal[0];
  const int run = (int)scal[1];
  for (int h = tid; h < 256; h += 256) hist[h] = 0;
  __syncthreads();                                             // B4
  for (int k = tid; k < NC_; k += 256)
    if ((ukey[k] >> 24) == beta) atomicAdd(&hist[(ukey[k] >> 16) & 0xFFu], 1u);
  __syncthreads();                                             // B5
  if (wid == 0) {
    int s4 = (int)(hist[lane * 4] + hist[lane * 4 + 1] + hist[lane * 4 + 2] + hist[lane * 4 + 3]);
    int s = s4;
#pragma unroll
    for (int off = 1; off < 64; off <<= 1) {
      int o = __shfl_down(s, off, 64);
      if (lane + off < 64) s += o;
    }
    int above = run + s - s4;
    if (above < KS_ && run + s >= KS_) {
      int r2 = above;
#pragma unroll
      for (int bb = 3; bb >= 0; --bb) {
        int h = (int)hist[lane * 4 + bb];
        if (r2 + h >= KS_) { scal[4] = (unsigned int)(lane * 4 + bb); scal[5] = (unsigned int)r2; break; }
        r2 += h;
      }
    }
  }
  __syncthreads();                                             // B6
  const unsigned int beta2 = scal[4];
  const int run2 = (int)scal[5];
  const size_t outb = ((size_t)t * NQ_ + q) * KS_;
  float lsum = 0.f;
  for (int k = tid; k < NC_; k += 256) {
    unsigned int key = ukey[k];
    unsigned int bin = key >> 24;
    bool sel = false, bdry = false;
    if (bin > beta) sel = true;
    else if (bin == beta) {
      unsigned int b2 = (key >> 16) & 0xFFu;
      if (b2 > beta2) sel = true;
      else if (b2 == beta2) bdry = true;
    }
    if (sel) {
      unsigned int slot = atomicAdd(&scal[2], 1u);
      int aa = k / 27, bb = k - aa * 27;
      int ni = min(max(qi + aa - 13, 0), H_ - 1);
      int nj = min(max(qj + bb - 13, 0), W_ - 1);
      float wv = __expf(SCALE_ * (dist[k] - dmax));
      sel_n[outb + slot] = (ni << 7) | nj;
      sel_w[outb + slot] = wv;
      lsum += wv;
    } else if (bdry) {
      unsigned int pos = atomicAdd(&scal[3], 1u);
      if (pos < LCAP_) { lk[pos] = k; lkey[pos] = key; }
    }
  }
  __syncthreads();                                             // B7
  const int L = min((int)scal[3], LCAP_);
  for (int i = tid; i < L; i += 256) {
    unsigned int key = lkey[i];
    int k = lk[i];
    int cnt = run2;
    for (int m = 0; m < L; ++m)
      cnt += (int)((lkey[m] > key) || (lkey[m] == key && lk[m] < k));
    if (cnt < KS_) {
      unsigned int slot = atomicAdd(&scal[2], 1u);
      int aa = k / 27, bb = k - aa * 27;
      int ni = min(max(qi + aa - 13, 0), H_ - 1);
      int nj = min(max(qj + bb - 13, 0), W_ - 1);
      float wv = __expf(SCALE_ * (dist[k] - dmax));
      sel_n[outb + slot] = (ni << 7) | nj;
      sel_w[outb + slot] = wv;
      lsum += wv;
    }
  }
#pragma unroll
  for (int off = 32; off > 0; off >>= 1) lsum += __shfl_down(lsum, off, 64);
  __syncthreads();                                             // B8
  if (lane == 0) redf[wid] = lsum;
  __syncthreads();                                             // B9
  if (tid == 0) wsum_out[t * NQ_ + q] = (redf[0] + redf[1]) + (redf[2] + redf[3]);
}

// ---------------- weighted aggregation + fold (4x4-tile LDS region) ---------
// 1024 threads = 16 waves = 16 queries sharing a 45x45 float4 region.
// L2 gather traffic (2.7 GB) -> coalesced staging (~33 MB) + LDS reads.
__global__ __launch_bounds__(1024) void agg_kernel(
    const float4* __restrict__ v2cs, const int* __restrict__ sel_n,
    const float* __restrict__ sel_w, const float* __restrict__ wsum,
    float* __restrict__ Y) {
  __shared__ float4 Rs[RW_ * RW_];
  __shared__ int s_off[16][KS_];
  __shared__ float s_w[16][KS_];
  const int tid = threadIdx.x;
  const int t = blockIdx.y;
  const int qi0 = (blockIdx.x >> 3) * 16, qj0 = (blockIdx.x & 7) * 16;
  const int w = tid >> 6, lane = tid & 63;
  const int di = (w >> 2) * 4, dj = (w & 3) * 4;
  const int qi = qi0 + di, qj = qj0 + dj;
  const int q = ((qi >> 2) << 5) + (qj >> 2);
  const size_t base = ((size_t)t * NQ_ + q) * KS_;
  const float inv = 1.0f / wsum[t * NQ_ + q];
  for (int k = lane; k < KS_; k += 64) {
    int n = sel_n[base + k];
    int ni = n >> 7, nj = n & 127;
    s_off[w][k] = (ni - qi0 + 13) * RW_ + (nj - qj0 + 13);
    s_w[w][k] = sel_w[base + k] * inv;
  }
  const int r = lane / 7, s = lane - r * 7;    // valid for lane < 49
  const int myo = r * RW_ + s;
  const int oi = min(qi + r, H_ - 1), oj = min(qj + s, W_ - 1);
#pragma unroll 1
  for (int cc = 0; cc < 4; ++cc) {
    __syncthreads();
    const float4* src = v2cs + ((size_t)cc * T_ + t) * HW_;
    for (int p = tid; p < RW_ * RW_; p += 1024) {
      int uu = p / RW_, vv = p - uu * RW_;
      int row = min(max(qi0 - 13 + uu, 0), H_ - 1);
      int col = min(max(qj0 - 13 + vv, 0), W_ - 1);
      Rs[p] = src[row * W_ + col];
    }
    __syncthreads();
    if (lane < 49) {
      float4 acc = make_float4(0.f, 0.f, 0.f, 0.f);
#pragma unroll 4
      for (int k = 0; k < KS_; ++k) {
        float wv = s_w[w][k];
        float4 v = Rs[s_off[w][k] + myo];
        acc.x = fmaf(wv, v.x, acc.x);
        acc.y = fmaf(wv, v.y, acc.y);
        acc.z = fmaf(wv, v.z, acc.z);
        acc.w = fmaf(wv, v.w, acc.w);
      }
      float* yb = Y + (((size_t)t * CI_ + cc * 4) * H_ + oi) * W_ + oj;
      atomicAdd(yb, acc.x);
      atomicAdd(yb + HW_, acc.y);
      atomicAdd(yb + 2 * HW_, acc.z);
      atomicAdd(yb + 3 * HW_, acc.w);
    }
  }
}

// ---------------- normalize by analytic fold counts -------------------------
__device__ __forceinline__ int cov_axis(int x) {
  int c = 0;
#pragma unroll
  for (int r = 0; r < 7; ++r) {
    if (x < H_ - 1) {
      int qb = x - r;
      c += (qb >= 0 && (qb & 3) == 0) ? 1 : 0;
    } else {
      c += (r >= 3) ? 1 : 0;
    }
  }
  return c;
}

__global__ void norm_kernel(float* __restrict__ Y) {
  int idx = blockIdx.x * blockDim.x + threadIdx.x;
  if (idx >= T_ * CI_ * HW_) return;
  int p = idx & (HW_ - 1);
  float z = (float)(cov_axis(p >> 7) * cov_axis(p & 127));
  Y[idx] /= z;
}

extern "C" void kernel_launch(void* const* d_in, const int* in_sizes, int n_in,
                              void* d_out, int out_size, void* d_ws, size_t ws_size,
                              hipStream_t stream) {
  const float* vid     = (const float*)d_in[0];
  const float* g_w     = (const float*)d_in[1];
  const float* g_b     = (const float*)d_in[2];
  const float* theta_w = (const float*)d_in[3];
  const float* theta_b = (const float*)d_in[4];
  float* Y = (float*)d_out;

  // workspace (floats): v1cs | v2cs | distG | sel_n | sel_w | wsum | distB
  float* v1cs  = (float*)d_ws;
  float* v2cs  = v1cs + (size_t)4 * T_ * HW_ * 4;              // 1048576
  float* distG = v2cs + (size_t)4 * T_ * HW_ * 4;              // 1048576
  int*   sel_n = (int*)(distG + (size_t)T_ * NQ_ * NC_);       // 2985984
  float* sel_w = (float*)(sel_n + (size_t)T_ * NQ_ * KS_);     // 409600
  float* wsumv = sel_w + (size_t)T_ * NQ_ * KS_;               // 409600
  float* distB = wsumv + (size_t)T_ * NQ_;                     // 4096

  // split mode needs the second partial-dist buffer (+~12 MB); gate on ws_size
  // (R5 ran dual on this harness => normally taken).
  const size_t need_dual =
      ((size_t)4 * T_ * HW_ * 4 * 2 + (size_t)T_ * NQ_ * NC_ * 2 +
       (size_t)T_ * NQ_ * KS_ * 2 + (size_t)T_ * NQ_) * sizeof(float);
  const int dual = (ws_size >= need_dual) ? 1 : 0;

  hipMemsetAsync(Y, 0, (size_t)out_size * sizeof(float), stream);
  if (!dual)
    hipMemsetAsync(distG, 0, (size_t)T_ * NQ_ * NC_ * sizeof(float), stream);

  conv3x3_kernel<<<dim3(64, 4, T_), 128, 0, stream>>>(vid, g_w, g_b, (float4*)v1cs);
  conv1x1_kernel<<<dim3(HW_ / 256, T_, 4), 256, 0, stream>>>(vid, theta_w, theta_b, (float4*)v2cs);
  dist_kernel<<<dim3(64, T_), 1024, 0, stream>>>(
      (const float4*)v1cs, distG, distB, dual ? 0 : 1);
  select_kernel<<<dim3(NQ_, T_), 256, 0, stream>>>(distG, distB, dual, sel_n, sel_w, wsumv);
  agg_kernel<<<dim3(64, T_), 1024, 0, stream>>>((const float4*)v2cs, sel_n, sel_w, wsumv, Y);
  norm_kernel<<<(T_ * CI_ * HW_ + 255) / 256, 256, 0, stream>>>(Y);
}

// Round 7
// 361.775 us; speedup vs baseline: 1.0078x; 1.0078x over previous
//
#include <hip/hip_runtime.h>
#include <hip/hip_bf16.h>

#define T_ 4
#define C_ 64
#define H_ 128
#define W_ 128
#define CI_ 16
#define PS_ 7
#define NC_ 729       // 27*27 candidates per query
#define S0_ 4
#define KS_ 100
#define NQ_ 1024      // 32*32 queries per frame
#define SCALE_ 10.0f
#define HW_ (H_*W_)
#define RW_ 45        // 4x4-tile region dim (float4); 45%8=5 -> bank rotation
#define LCAP_ 768
#define CB_ 8         // conv3x3 channel batch (24 dwordx4 in flight)

typedef float v2f __attribute__((ext_vector_type(2)));
#if __has_builtin(__builtin_elementwise_fma)
#define VFMA(a, b, c) __builtin_elementwise_fma((a), (b), (c))
#else
#define VFMA(a, b, c) ((a) * (b) + (c))
#endif

// ---------------- conv 3x3, 64->16, BRANCH-FREE batched loads ---------------
__device__ __forceinline__ float4 colfix(float4 r, bool loB, bool hiB) {
  float4 o;
  o.x = loB ? 0.f : (hiB ? r.y : r.x);
  o.y = loB ? r.x : (hiB ? r.z : r.y);
  o.z = loB ? r.y : (hiB ? r.w : r.z);
  o.w = loB ? r.z : (hiB ? 0.f : r.w);
  return o;
}

__global__ __launch_bounds__(128, 1) void conv3x3_kernel(
    const float* __restrict__ vid, const float* __restrict__ gw,
    const float* __restrict__ gb, float4* __restrict__ v1cs) {
  __shared__ float wls[C_ * 9 * 4];   // [c][k][co]
  const int tid = threadIdx.x;
  const int g = blockIdx.y, t = blockIdx.z;
  for (int m = tid; m < C_ * 9 * 4; m += 128) {
    int co = m & 3, ck = m >> 2;
    wls[m] = gw[((size_t)(g * 4 + co) * C_) * 9 + ck];
  }
  __syncthreads();
  const int ti0 = (blockIdx.x >> 3) * 16, tj0 = (blockIdx.x & 7) * 16;
  const int u = tid >> 3, v = tid & 7;   // 16 rows x 8 col-pairs
  const int i = ti0 + u, j0 = tj0 + 2 * v;
  const int c0 = j0 - 1;
  const int c0c = min(max(c0, 0), W_ - 4);
  const bool loB = (c0 < 0), hiB = (c0 > W_ - 4);
  const int rm1 = max(i - 1, 0), rp1 = min(i + 1, H_ - 1);
  const float mk0 = (i > 0) ? 1.f : 0.f;
  const float mk2 = (i < H_ - 1) ? 1.f : 0.f;
  const int o0 = rm1 * W_ + c0c, o1 = i * W_ + c0c, o2 = rp1 * W_ + c0c;

  float accA[4], accB[4];
#pragma unroll
  for (int co = 0; co < 4; ++co) { accA[co] = gb[g * 4 + co]; accB[co] = gb[g * 4 + co]; }

  const float* vb = vid + ((size_t)t * C_) * HW_;
#pragma unroll 1
  for (int cb = 0; cb < C_; cb += CB_) {
    float4 r[CB_][3];
#pragma unroll
    for (int c = 0; c < CB_; ++c) {       // 24 UNCONDITIONAL loads -> in flight
      const float* p = vb + (size_t)(cb + c) * HW_;
      r[c][0] = *(const float4*)(p + o0);
      r[c][1] = *(const float4*)(p + o1);
      r[c][2] = *(const float4*)(p + o2);
    }
#pragma unroll
    for (int c = 0; c < CB_; ++c) {
      float4 f0 = colfix(r[c][0], loB, hiB);
      float4 f1 = colfix(r[c][1], loB, hiB);
      float4 f2 = colfix(r[c][2], loB, hiB);
      f0.x *= mk0; f0.y *= mk0; f0.z *= mk0; f0.w *= mk0;
      f2.x *= mk2; f2.y *= mk2; f2.z *= mk2; f2.w *= mk2;
      const float* wc = &wls[(cb + c) * 36];
      float e0[4] = {f0.x, f0.y, f0.z, f0.w};
      float e1[4] = {f1.x, f1.y, f1.z, f1.w};
      float e2[4] = {f2.x, f2.y, f2.z, f2.w};
#pragma unroll
      for (int kj = 0; kj < 3; ++kj) {
#pragma unroll
        for (int co = 0; co < 4; ++co) {
          accA[co] = fmaf(wc[(0 * 3 + kj) * 4 + co], e0[kj],     accA[co]);
          accB[co] = fmaf(wc[(0 * 3 + kj) * 4 + co], e0[kj + 1], accB[co]);
          accA[co] = fmaf(wc[(1 * 3 + kj) * 4 + co], e1[kj],     accA[co]);
          accB[co] = fmaf(wc[(1 * 3 + kj) * 4 + co], e1[kj + 1], accB[co]);
          accA[co] = fmaf(wc[(2 * 3 + kj) * 4 + co], e2[kj],     accA[co]);
          accB[co] = fmaf(wc[(2 * 3 + kj) * 4 + co], e2[kj + 1], accB[co]);
        }
      }
    }
  }
  const size_t o = ((size_t)g * T_ + t) * HW_ + i * W_ + j0;
  v1cs[o]     = make_float4(accA[0], accA[1], accA[2], accA[3]);
  v1cs[o + 1] = make_float4(accB[0], accB[1], accB[2], accB[3]);
}

// ---------------- conv 1x1, 64->16, chunk-major float4 output ----------------
__global__ __launch_bounds__(256, 1) void conv1x1_kernel(
    const float* __restrict__ vid, const float* __restrict__ tw,
    const float* __restrict__ tb, float4* __restrict__ v2cs) {
  __shared__ float w[C_ * 4];
  const int t = blockIdx.y, cc = blockIdx.z;
  for (int m = threadIdx.x; m < C_ * 4; m += 256) {
    int o = m & 3, c = m >> 2;
    w[m] = tw[(cc * 4 + o) * C_ + c];
  }
  __syncthreads();
  const int pix = blockIdx.x * 256 + threadIdx.x;
  float acc[4];
#pragma unroll
  for (int o = 0; o < 4; ++o) acc[o] = tb[cc * 4 + o];
  const float* vb = vid + ((size_t)t * C_) * HW_ + pix;
#pragma unroll 1
  for (int c0 = 0; c0 < C_; c0 += 16) {
    float x[16];
#pragma unroll
    for (int uu = 0; uu < 16; ++uu) x[uu] = vb[(size_t)(c0 + uu) * HW_];
#pragma unroll
    for (int uu = 0; uu < 16; ++uu)
#pragma unroll
      for (int o = 0; o < 4; ++o)
        acc[o] = fmaf(w[(c0 + uu) * 4 + o], x[uu], acc[o]);
  }
  v2cs[((size_t)cc * T_ + t) * HW_ + pix] = make_float4(acc[0], acc[1], acc[2], acc[3]);
}

// ---------------- dists: 1024-thr block = pair-trick + r-split --------------
// 16 waves co-resident (intra-block => guaranteed 4 waves/SIMD; R5 showed the
// dispatcher won't co-schedule separate blocks). Waves 0-7: pair geometry
// (16 queries, lane la in [0,30] serves q0 at a=la and q1=+4 rows at a=la-4),
// patch rows r=0..3. Waves 8-15: same queries, rows r=4..6. Partial dists go
// to distG / distB; select sums (dual).
// launch_bounds (1024, 1): hipcc's 2nd arg acts as min BLOCKS/CU (CUDA
// semantics -- verified R3/R4/R6: (512,2)->128cap/84, (512,4)->64/spill,
// (1024,4)->64/spill+475MB scratch). 1 block/CU = 4 waves/SIMD = 128 VGPR cap;
// natural demand ~84. NEVER ask for >1 block of 1024 threads.
__global__ __launch_bounds__(1024, 1) void dist_kernel(
    const float4* __restrict__ v1cs, float* __restrict__ distG,
    float* __restrict__ distB, int use_atomic) {
  __shared__ float4 Rs[2][2025];
  const int tid = threadIdx.x;
  const int t = blockIdx.y;
  const int qi0 = (blockIdx.x >> 3) * 16, qj0 = (blockIdx.x & 7) * 16;
  const int w = tid >> 6, lane = tid & 63;
  const int ws = w & 7, rset = w >> 3;           // 8 pair-configs x 2 r-sets
  const int r0 = rset ? 4 : 0, r1 = rset ? 7 : 4;
  const int pr = ws >> 2, dj = (ws & 3) * 4;     // pair-row {0,1}, col-tile
  const int rbase = 8 * pr;
  const int qi_p = qi0 + rbase;                  // q0 pixel row; q1 = qi_p+4
  const int qj = qj0 + dj;
  const int la = lane >> 1, bg = lane & 1;
  const int b_lo = max(13 - qj, 0);
  const int bs = bg ? 13 : b_lo;
  const int a_lo0 = max(13 - qi_p, 0);
  const int a_lo1 = max(9 - qi_p, 0);
  const bool compute_ok = (la < 31);
  const bool bdup = (bg == 0) && (b_lo == 13);   // qj==0: bg0 duplicates bg1

  // staging: 2 float4 per thread per chunk; clamped source, linear dest
  int soff[2];
#pragma unroll
  for (int k = 0; k < 2; ++k) {
    int p = min(tid + 1024 * k, RW_ * RW_ - 1);
    int uu = p / RW_, vv = p - uu * RW_;
    int row = min(max(qi0 - 13 + uu, 0), H_ - 1);
    int col = min(max(qj0 - 13 + vv, 0), W_ - 1);
    soff[k] = row * W_ + col;
  }
  const int d0 = tid, d1 = min(tid + 1024, RW_ * RW_ - 1);  // dup-writes benign

  v2f acc0[14], acc1[14];
#pragma unroll
  for (int j = 0; j < 14; ++j) { acc0[j] = (v2f){0.f, 0.f}; acc1[j] = (v2f){0.f, 0.f}; }

  float4 st[2];
  {
    const float4* src = v1cs + ((size_t)0 * T_ + t) * HW_;
    st[0] = src[soff[0]];
    st[1] = src[soff[1]];
  }
  int cur = 0;
#pragma unroll 1
  for (int ci = 0; ci < 4; ++ci) {
    float4* buf = &Rs[cur][0];
    buf[d0] = st[0];                              // stage chunk ci
    buf[d1] = st[1];
    if (ci < 3) {                                 // prefetch chunk ci+1
      const float4* src = v1cs + ((size_t)(ci + 1) * T_ + t) * HW_;
      st[0] = src[soff[0]];
      st[1] = src[soff[1]];
    }
    __syncthreads();                              // buf[cur] ready
    if (compute_ok) {
#pragma unroll 1
      for (int r = r0; r < r1; ++r) {
        v2f q0lo[7], q0hi[7], q1lo[7], q1hi[7];
        const float4* q0row = &buf[(rbase + 13 + r) * RW_ + dj + 13];
#pragma unroll
        for (int s = 0; s < 7; ++s) {
          float4 qq = q0row[s];                   // q0 patch row (broadcast)
          q0lo[s] = (v2f){qq.x, qq.y};
          q0hi[s] = (v2f){qq.z, qq.w};
          float4 q2 = q0row[4 * RW_ + s];         // q1 patch row = +4 rows
          q1lo[s] = (v2f){q2.x, q2.y};
          q1hi[s] = (v2f){q2.z, q2.w};
        }
        const float4* crow = &buf[(rbase + la + r) * RW_ + dj + bs];
#pragma unroll
        for (int y = 0; y < 20; ++y) {
          float4 vv4 = crow[y];                   // shared by q0 AND q1
          v2f vlo = (v2f){vv4.x, vv4.y}, vhi = (v2f){vv4.z, vv4.w};
          const int s_lo = (y > 13) ? (y - 13) : 0;
          const int s_hi = (y < 6) ? y : 6;
#pragma unroll
          for (int s = s_lo; s <= s_hi; ++s) {
            int j = y - s;
            acc0[j] = VFMA(q0lo[s], vlo, acc0[j]);
            acc0[j] = VFMA(q0hi[s], vhi, acc0[j]);
            acc1[j] = VFMA(q1lo[s], vlo, acc1[j]);
            acc1[j] = VFMA(q1hi[s], vhi, acc1[j]);
          }
        }
      }
    }
    __syncthreads();                              // all reads done before re-stage
    cur ^= 1;
  }
  if (compute_ok) {
    float* outB = (rset && !use_atomic) ? distB : distG;
    const int q0q = ((qi_p >> 2) << 5) + (qj >> 2);
    if (la >= a_lo0 && la <= 26 && !(use_atomic && bdup)) {
      float* out = outB + ((size_t)t * NQ_ + q0q) * NC_ + la * 27 + bs;
      if (use_atomic) {
#pragma unroll
        for (int j = 0; j < 14; ++j) atomicAdd(out + j, acc0[j].x + acc0[j].y);
      } else {
#pragma unroll
        for (int j = 0; j < 14; ++j) out[j] = acc0[j].x + acc0[j].y;
      }
    }
    const int a1 = la - 4;
    if (a1 >= a_lo1 && a1 <= 26 && !(use_atomic && bdup)) {
      float* out = outB + ((size_t)t * NQ_ + (q0q + 32)) * NC_ + a1 * 27 + bs;
      if (use_atomic) {
#pragma unroll
        for (int j = 0; j < 14; ++j) atomicAdd(out + j, acc1[j].x + acc1[j].y);
      } else {
#pragma unroll
        for (int j = 0; j < 14; ++j) out[j] = acc1[j].x + acc1[j].y;
      }
    }
  }
}

// ---------------- select: 2-level radix top-100, wave-primitive scans -------
__global__ __launch_bounds__(256) void select_kernel(
    const float* __restrict__ distA, const float* __restrict__ distB, int dual,
    int* __restrict__ sel_n, float* __restrict__ sel_w,
    float* __restrict__ wsum_out) {
  __shared__ float dist[NC_];
  __shared__ unsigned int ukey[NC_];
  __shared__ float redf[4];
  __shared__ unsigned int hist[256];
  __shared__ int lk[LCAP_];
  __shared__ unsigned int lkey[LCAP_];
  __shared__ unsigned int scal[6];   // 0=beta 1=run 2=cursor 3=listlen 4=beta2 5=run2

  const int tid = threadIdx.x;
  const int lane = tid & 63, wid = tid >> 6;
  const int q = blockIdx.x, t = blockIdx.y;
  const int qi = (q >> 5) * S0_, qj = (q & 31) * S0_;
  const int a_lo = max(13 - qi, 0), b_lo = max(13 - qj, 0);
  const size_t base = ((size_t)t * NQ_ + q) * NC_;

  for (int h = tid; h < 256; h += 256) hist[h] = 0;
  if (tid == 0) { scal[2] = 0; scal[3] = 0; }
  float lmax = -INFINITY;
  for (int k = tid; k < NC_; k += 256) {
    int aa = k / 27, bb = k - aa * 27;
    int kk = max(aa, a_lo) * 27 + max(bb, b_lo);
    float d = distA[base + kk];
    if (dual) d += distB[base + kk];
    dist[k] = d;
    unsigned int u = __float_as_uint(d);
    ukey[k] = u ^ (((unsigned int)((int)u >> 31)) | 0x80000000u);
    lmax = fmaxf(lmax, d);
  }
#pragma unroll
  for (int off = 32; off > 0; off >>= 1)
    lmax = fmaxf(lmax, __shfl_down(lmax, off, 64));
  if (lane == 0) redf[wid] = lmax;
  __syncthreads();                                             // B1
  const float dmax = fmaxf(fmaxf(redf[0], redf[1]), fmaxf(redf[2], redf[3]));
  for (int k = tid; k < NC_; k += 256) atomicAdd(&hist[ukey[k] >> 24], 1u);
  __syncthreads();                                             // B2
  if (wid == 0) {
    int s4 = (int)(hist[lane * 4] + hist[lane * 4 + 1] + hist[lane * 4 + 2] + hist[lane * 4 + 3]);
    int s = s4;
#pragma unroll
    for (int off = 1; off < 64; off <<= 1) {
      int o = __shfl_down(s, off, 64);
      if (lane + off < 64) s += o;
    }
    int above = s - s4;
    if (above < KS_ && s >= KS_) {
      int run = above;
#pragma unroll
      for (int bb = 3; bb >= 0; --bb) {
        int h = (int)hist[lane * 4 + bb];
        if (run + h >= KS_) { scal[0] = (unsigned int)(lane * 4 + bb); scal[1] = (unsigned int)run; break; }
        run += h;
      }
    }
  }
  __syncthreads();                                             // B3
  const unsigned int beta = scal[0];
  const int run = (int)scal[1];
  for (int h = tid; h < 256; h += 256) hist[h] = 0;
  __syncthreads();                                             // B4
  for (int k = tid; k < NC_; k += 256)
    if ((ukey[k] >> 24) == beta) atomicAdd(&hist[(ukey[k] >> 16) & 0xFFu], 1u);
  __syncthreads();                                             // B5
  if (wid == 0) {
    int s4 = (int)(hist[lane * 4] + hist[lane * 4 + 1] + hist[lane * 4 + 2] + hist[lane * 4 + 3]);
    int s = s4;
#pragma unroll
    for (int off = 1; off < 64; off <<= 1) {
      int o = __shfl_down(s, off, 64);
      if (lane + off < 64) s += o;
    }
    int above = run + s - s4;
    if (above < KS_ && run + s >= KS_) {
      int r2 = above;
#pragma unroll
      for (int bb = 3; bb >= 0; --bb) {
        int h = (int)hist[lane * 4 + bb];
        if (r2 + h >= KS_) { scal[4] = (unsigned int)(lane * 4 + bb); scal[5] = (unsigned int)r2; break; }
        r2 += h;
      }
    }
  }
  __syncthreads();                                             // B6
  const unsigned int beta2 = scal[4];
  const int run2 = (int)scal[5];
  const size_t outb = ((size_t)t * NQ_ + q) * KS_;
  float lsum = 0.f;
  for (int k = tid; k < NC_; k += 256) {
    unsigned int key = ukey[k];
    unsigned int bin = key >> 24;
    bool sel = false, bdry = false;
    if (bin > beta) sel = true;
    else if (bin == beta) {
      unsigned int b2 = (key >> 16) & 0xFFu;
      if (b2 > beta2) sel = true;
      else if (b2 == beta2) bdry = true;
    }
    if (sel) {
      unsigned int slot = atomicAdd(&scal[2], 1u);
      int aa = k / 27, bb = k - aa * 27;
      int ni = min(max(qi + aa - 13, 0), H_ - 1);
      int nj = min(max(qj + bb - 13, 0), W_ - 1);
      float wv = __expf(SCALE_ * (dist[k] - dmax));
      sel_n[outb + slot] = (ni << 7) | nj;
      sel_w[outb + slot] = wv;
      lsum += wv;
    } else if (bdry) {
      unsigned int pos = atomicAdd(&scal[3], 1u);
      if (pos < LCAP_) { lk[pos] = k; lkey[pos] = key; }
    }
  }
  __syncthreads();                                             // B7
  const int L = min((int)scal[3], LCAP_);
  for (int i = tid; i < L; i += 256) {
    unsigned int key = lkey[i];
    int k = lk[i];
    int cnt = run2;
    for (int m = 0; m < L; ++m)
      cnt += (int)((lkey[m] > key) || (lkey[m] == key && lk[m] < k));
    if (cnt < KS_) {
      unsigned int slot = atomicAdd(&scal[2], 1u);
      int aa = k / 27, bb = k - aa * 27;
      int ni = min(max(qi + aa - 13, 0), H_ - 1);
      int nj = min(max(qj + bb - 13, 0), W_ - 1);
      float wv = __expf(SCALE_ * (dist[k] - dmax));
      sel_n[outb + slot] = (ni << 7) | nj;
      sel_w[outb + slot] = wv;
      lsum += wv;
    }
  }
#pragma unroll
  for (int off = 32; off > 0; off >>= 1) lsum += __shfl_down(lsum, off, 64);
  __syncthreads();                                             // B8
  if (lane == 0) redf[wid] = lsum;
  __syncthreads();                                             // B9
  if (tid == 0) wsum_out[t * NQ_ + q] = (redf[0] + redf[1]) + (redf[2] + redf[3]);
}

// ---------------- weighted aggregation + fold (4x4-tile LDS region) ---------
// 1024 threads = 16 waves = 16 queries sharing a 45x45 float4 region.
// L2 gather traffic (2.7 GB) -> coalesced staging (~33 MB) + LDS reads.
__global__ __launch_bounds__(1024) void agg_kernel(
    const float4* __restrict__ v2cs, const int* __restrict__ sel_n,
    const float* __restrict__ sel_w, const float* __restrict__ wsum,
    float* __restrict__ Y) {
  __shared__ float4 Rs[RW_ * RW_];
  __shared__ int s_off[16][KS_];
  __shared__ float s_w[16][KS_];
  const int tid = threadIdx.x;
  const int t = blockIdx.y;
  const int qi0 = (blockIdx.x >> 3) * 16, qj0 = (blockIdx.x & 7) * 16;
  const int w = tid >> 6, lane = tid & 63;
  const int di = (w >> 2) * 4, dj = (w & 3) * 4;
  const int qi = qi0 + di, qj = qj0 + dj;
  const int q = ((qi >> 2) << 5) + (qj >> 2);
  const size_t base = ((size_t)t * NQ_ + q) * KS_;
  const float inv = 1.0f / wsum[t * NQ_ + q];
  for (int k = lane; k < KS_; k += 64) {
    int n = sel_n[base + k];
    int ni = n >> 7, nj = n & 127;
    s_off[w][k] = (ni - qi0 + 13) * RW_ + (nj - qj0 + 13);
    s_w[w][k] = sel_w[base + k] * inv;
  }
  const int r = lane / 7, s = lane - r * 7;    // valid for lane < 49
  const int myo = r * RW_ + s;
  const int oi = min(qi + r, H_ - 1), oj = min(qj + s, W_ - 1);
#pragma unroll 1
  for (int cc = 0; cc < 4; ++cc) {
    __syncthreads();
    const float4* src = v2cs + ((size_t)cc * T_ + t) * HW_;
    for (int p = tid; p < RW_ * RW_; p += 1024) {
      int uu = p / RW_, vv = p - uu * RW_;
      int row = min(max(qi0 - 13 + uu, 0), H_ - 1);
      int col = min(max(qj0 - 13 + vv, 0), W_ - 1);
      Rs[p] = src[row * W_ + col];
    }
    __syncthreads();
    if (lane < 49) {
      float4 acc = make_float4(0.f, 0.f, 0.f, 0.f);
#pragma unroll 4
      for (int k = 0; k < KS_; ++k) {
        float wv = s_w[w][k];
        float4 v = Rs[s_off[w][k] + myo];
        acc.x = fmaf(wv, v.x, acc.x);
        acc.y = fmaf(wv, v.y, acc.y);
        acc.z = fmaf(wv, v.z, acc.z);
        acc.w = fmaf(wv, v.w, acc.w);
      }
      float* yb = Y + (((size_t)t * CI_ + cc * 4) * H_ + oi) * W_ + oj;
      atomicAdd(yb, acc.x);
      atomicAdd(yb + HW_, acc.y);
      atomicAdd(yb + 2 * HW_, acc.z);
      atomicAdd(yb + 3 * HW_, acc.w);
    }
  }
}

// ---------------- normalize by analytic fold counts -------------------------
__device__ __forceinline__ int cov_axis(int x) {
  int c = 0;
#pragma unroll
  for (int r = 0; r < 7; ++r) {
    if (x < H_ - 1) {
      int qb = x - r;
      c += (qb >= 0 && (qb & 3) == 0) ? 1 : 0;
    } else {
      c += (r >= 3) ? 1 : 0;
    }
  }
  return c;
}

__global__ void norm_kernel(float* __restrict__ Y) {
  int idx = blockIdx.x * blockDim.x + threadIdx.x;
  if (idx >= T_ * CI_ * HW_) return;
  int p = idx & (HW_ - 1);
  float z = (float)(cov_axis(p >> 7) * cov_axis(p & 127));
  Y[idx] /= z;
}

extern "C" void kernel_launch(void* const* d_in, const int* in_sizes, int n_in,
                              void* d_out, int out_size, void* d_ws, size_t ws_size,
                              hipStream_t stream) {
  const float* vid     = (const float*)d_in[0];
  const float* g_w     = (const float*)d_in[1];
  const float* g_b     = (const float*)d_in[2];
  const float* theta_w = (const float*)d_in[3];
  const float* theta_b = (const float*)d_in[4];
  float* Y = (float*)d_out;

  // workspace (floats): v1cs | v2cs | distG | sel_n | sel_w | wsum | distB
  float* v1cs  = (float*)d_ws;
  float* v2cs  = v1cs + (size_t)4 * T_ * HW_ * 4;              // 1048576
  float* distG = v2cs + (size_t)4 * T_ * HW_ * 4;              // 1048576
  int*   sel_n = (int*)(distG + (size_t)T_ * NQ_ * NC_);       // 2985984
  float* sel_w = (float*)(sel_n + (size_t)T_ * NQ_ * KS_);     // 409600
  float* wsumv = sel_w + (size_t)T_ * NQ_ * KS_;               // 409600
  float* distB = wsumv + (size_t)T_ * NQ_;                     // 4096

  // split mode needs the second partial-dist buffer (+~12 MB); gate on ws_size
  // (R5/R6 ran dual on this harness => normally taken).
  const size_t need_dual =
      ((size_t)4 * T_ * HW_ * 4 * 2 + (size_t)T_ * NQ_ * NC_ * 2 +
       (size_t)T_ * NQ_ * KS_ * 2 + (size_t)T_ * NQ_) * sizeof(float);
  const int dual = (ws_size >= need_dual) ? 1 : 0;

  hipMemsetAsync(Y, 0, (size_t)out_size * sizeof(float), stream);
  if (!dual)
    hipMemsetAsync(distG, 0, (size_t)T_ * NQ_ * NC_ * sizeof(float), stream);

  conv3x3_kernel<<<dim3(64, 4, T_), 128, 0, stream>>>(vid, g_w, g_b, (float4*)v1cs);
  conv1x1_kernel<<<dim3(HW_ / 256, T_, 4), 256, 0, stream>>>(vid, theta_w, theta_b, (float4*)v2cs);
  dist_kernel<<<dim3(64, T_), 1024, 0, stream>>>(
      (const float4*)v1cs, distG, distB, dual ? 0 : 1);
  select_kernel<<<dim3(NQ_, T_), 256, 0, stream>>>(distG, distB, dual, sel_n, sel_w, wsumv);
  agg_kernel<<<dim3(64, T_), 1024, 0, stream>>>((const float4*)v2cs, sel_n, sel_w, wsumv, Y);
  norm_kernel<<<(T_ * CI_ * HW_ + 255) / 256, 256, 0, stream>>>(Y);
}

// Round 8
// 346.377 us; speedup vs baseline: 1.0526x; 1.0445x over previous
//
#include <hip/hip_runtime.h>
#include <hip/hip_bf16.h>

#define T_ 4
#define C_ 64
#define H_ 128
#define W_ 128
#define CI_ 16
#define PS_ 7
#define NC_ 729       // 27*27 candidates per query
#define S0_ 4
#define KS_ 100
#define NQ_ 1024      // 32*32 queries per frame
#define SCALE_ 10.0f
#define HW_ (H_*W_)
#define RW_ 45        // 4x4-tile region dim (float4); 45%8=5 -> bank rotation
#define LCAP_ 768
#define CB_ 8         // conv3x3 channel batch (24 dwordx4 in flight)
#define LBUF_ 2592    // LDS buffer stride: 2x2592x16B = 82944B > 80KiB so only
                      // ONE 1024-thr block fits/CU -> backend budgets 128 VGPR
                      // (R3-R7: VGPR cap tracks LDS-achievable occupancy)

typedef float v2f __attribute__((ext_vector_type(2)));
#if __has_builtin(__builtin_elementwise_fma)
#define VFMA(a, b, c) __builtin_elementwise_fma((a), (b), (c))
#else
#define VFMA(a, b, c) ((a) * (b) + (c))
#endif

// ---------------- conv 3x3, 64->16, BRANCH-FREE batched loads ---------------
__device__ __forceinline__ float4 colfix(float4 r, bool loB, bool hiB) {
  float4 o;
  o.x = loB ? 0.f : (hiB ? r.y : r.x);
  o.y = loB ? r.x : (hiB ? r.z : r.y);
  o.z = loB ? r.y : (hiB ? r.w : r.z);
  o.w = loB ? r.z : (hiB ? 0.f : r.w);
  return o;
}

__global__ __launch_bounds__(128, 1) void conv3x3_kernel(
    const float* __restrict__ vid, const float* __restrict__ gw,
    const float* __restrict__ gb, float4* __restrict__ v1cs) {
  __shared__ float wls[C_ * 9 * 4];   // [c][k][co]
  const int tid = threadIdx.x;
  const int g = blockIdx.y, t = blockIdx.z;
  for (int m = tid; m < C_ * 9 * 4; m += 128) {
    int co = m & 3, ck = m >> 2;
    wls[m] = gw[((size_t)(g * 4 + co) * C_) * 9 + ck];
  }
  __syncthreads();
  const int ti0 = (blockIdx.x >> 3) * 16, tj0 = (blockIdx.x & 7) * 16;
  const int u = tid >> 3, v = tid & 7;   // 16 rows x 8 col-pairs
  const int i = ti0 + u, j0 = tj0 + 2 * v;
  const int c0 = j0 - 1;
  const int c0c = min(max(c0, 0), W_ - 4);
  const bool loB = (c0 < 0), hiB = (c0 > W_ - 4);
  const int rm1 = max(i - 1, 0), rp1 = min(i + 1, H_ - 1);
  const float mk0 = (i > 0) ? 1.f : 0.f;
  const float mk2 = (i < H_ - 1) ? 1.f : 0.f;
  const int o0 = rm1 * W_ + c0c, o1 = i * W_ + c0c, o2 = rp1 * W_ + c0c;

  float accA[4], accB[4];
#pragma unroll
  for (int co = 0; co < 4; ++co) { accA[co] = gb[g * 4 + co]; accB[co] = gb[g * 4 + co]; }

  const float* vb = vid + ((size_t)t * C_) * HW_;
#pragma unroll 1
  for (int cb = 0; cb < C_; cb += CB_) {
    float4 r[CB_][3];
#pragma unroll
    for (int c = 0; c < CB_; ++c) {       // 24 UNCONDITIONAL loads -> in flight
      const float* p = vb + (size_t)(cb + c) * HW_;
      r[c][0] = *(const float4*)(p + o0);
      r[c][1] = *(const float4*)(p + o1);
      r[c][2] = *(const float4*)(p + o2);
    }
#pragma unroll
    for (int c = 0; c < CB_; ++c) {
      float4 f0 = colfix(r[c][0], loB, hiB);
      float4 f1 = colfix(r[c][1], loB, hiB);
      float4 f2 = colfix(r[c][2], loB, hiB);
      f0.x *= mk0; f0.y *= mk0; f0.z *= mk0; f0.w *= mk0;
      f2.x *= mk2; f2.y *= mk2; f2.z *= mk2; f2.w *= mk2;
      const float* wc = &wls[(cb + c) * 36];
      float e0[4] = {f0.x, f0.y, f0.z, f0.w};
      float e1[4] = {f1.x, f1.y, f1.z, f1.w};
      float e2[4] = {f2.x, f2.y, f2.z, f2.w};
#pragma unroll
      for (int kj = 0; kj < 3; ++kj) {
#pragma unroll
        for (int co = 0; co < 4; ++co) {
          accA[co] = fmaf(wc[(0 * 3 + kj) * 4 + co], e0[kj],     accA[co]);
          accB[co] = fmaf(wc[(0 * 3 + kj) * 4 + co], e0[kj + 1], accB[co]);
          accA[co] = fmaf(wc[(1 * 3 + kj) * 4 + co], e1[kj],     accA[co]);
          accB[co] = fmaf(wc[(1 * 3 + kj) * 4 + co], e1[kj + 1], accB[co]);
          accA[co] = fmaf(wc[(2 * 3 + kj) * 4 + co], e2[kj],     accA[co]);
          accB[co] = fmaf(wc[(2 * 3 + kj) * 4 + co], e2[kj + 1], accB[co]);
        }
      }
    }
  }
  const size_t o = ((size_t)g * T_ + t) * HW_ + i * W_ + j0;
  v1cs[o]     = make_float4(accA[0], accA[1], accA[2], accA[3]);
  v1cs[o + 1] = make_float4(accB[0], accB[1], accB[2], accB[3]);
}

// ---------------- conv 1x1, 64->16, chunk-major float4 output ----------------
__global__ __launch_bounds__(256, 1) void conv1x1_kernel(
    const float* __restrict__ vid, const float* __restrict__ tw,
    const float* __restrict__ tb, float4* __restrict__ v2cs) {
  __shared__ float w[C_ * 4];
  const int t = blockIdx.y, cc = blockIdx.z;
  for (int m = threadIdx.x; m < C_ * 4; m += 256) {
    int o = m & 3, c = m >> 2;
    w[m] = tw[(cc * 4 + o) * C_ + c];
  }
  __syncthreads();
  const int pix = blockIdx.x * 256 + threadIdx.x;
  float acc[4];
#pragma unroll
  for (int o = 0; o < 4; ++o) acc[o] = tb[cc * 4 + o];
  const float* vb = vid + ((size_t)t * C_) * HW_ + pix;
#pragma unroll 1
  for (int c0 = 0; c0 < C_; c0 += 16) {
    float x[16];
#pragma unroll
    for (int uu = 0; uu < 16; ++uu) x[uu] = vb[(size_t)(c0 + uu) * HW_];
#pragma unroll
    for (int uu = 0; uu < 16; ++uu)
#pragma unroll
      for (int o = 0; o < 4; ++o)
        acc[o] = fmaf(w[(c0 + uu) * 4 + o], x[uu], acc[o]);
  }
  v2cs[((size_t)cc * T_ + t) * HW_ + pix] = make_float4(acc[0], acc[1], acc[2], acc[3]);
}

// ---------------- dists: 1024-thr block = pair-trick + r-split --------------
// 16 waves co-resident (intra-block). Waves 0-7: pair geometry (16 queries,
// lane la in [0,30] serves q0 at a=la and q1=+4 rows at a=la-4), rows r=0..3.
// Waves 8-15: same queries, rows r=4..6. Partials to distG/distB; select sums.
// VGPR budget: backend caps VGPRs at the LDS-achievable occupancy (R3-R7
// evidence: 63.5KiB LDS -> 2 blocks/CU "achievable" -> 8 w/EU -> 64 VGPR ->
// ~90-reg spill, 475MB scratch, 173us). Two-sided fix: waves_per_eu(4,4)
// pins the target at 4 w/EU (128 VGPR), and LBUF_ pads LDS to 82944B so only
// one block fits/CU (grid is 1 block/CU anyway -- zero cost).
__global__ __launch_bounds__(1024)
__attribute__((amdgpu_waves_per_eu(4, 4)))
void dist_kernel(
    const float4* __restrict__ v1cs, float* __restrict__ distG,
    float* __restrict__ distB, int use_atomic) {
  __shared__ float4 Rs[2][LBUF_];
  const int tid = threadIdx.x;
  const int t = blockIdx.y;
  const int qi0 = (blockIdx.x >> 3) * 16, qj0 = (blockIdx.x & 7) * 16;
  const int w = tid >> 6, lane = tid & 63;
  const int ws = w & 7, rset = w >> 3;           // 8 pair-configs x 2 r-sets
  const int r0 = rset ? 4 : 0, r1 = rset ? 7 : 4;
  const int pr = ws >> 2, dj = (ws & 3) * 4;     // pair-row {0,1}, col-tile
  const int rbase = 8 * pr;
  const int qi_p = qi0 + rbase;                  // q0 pixel row; q1 = qi_p+4
  const int qj = qj0 + dj;
  const int la = lane >> 1, bg = lane & 1;
  const int b_lo = max(13 - qj, 0);
  const int bs = bg ? 13 : b_lo;
  const int a_lo0 = max(13 - qi_p, 0);
  const int a_lo1 = max(9 - qi_p, 0);
  const bool compute_ok = (la < 31);
  const bool bdup = (bg == 0) && (b_lo == 13);   // qj==0: bg0 duplicates bg1

  // staging: 2 float4 per thread per chunk; clamped source, linear dest
  int soff[2];
#pragma unroll
  for (int k = 0; k < 2; ++k) {
    int p = min(tid + 1024 * k, RW_ * RW_ - 1);
    int uu = p / RW_, vv = p - uu * RW_;
    int row = min(max(qi0 - 13 + uu, 0), H_ - 1);
    int col = min(max(qj0 - 13 + vv, 0), W_ - 1);
    soff[k] = row * W_ + col;
  }
  const int d0 = tid, d1 = min(tid + 1024, RW_ * RW_ - 1);  // dup-writes benign

  v2f acc0[14], acc1[14];
#pragma unroll
  for (int j = 0; j < 14; ++j) { acc0[j] = (v2f){0.f, 0.f}; acc1[j] = (v2f){0.f, 0.f}; }

  float4 st[2];
  {
    const float4* src = v1cs + ((size_t)0 * T_ + t) * HW_;
    st[0] = src[soff[0]];
    st[1] = src[soff[1]];
  }
  int cur = 0;
#pragma unroll 1
  for (int ci = 0; ci < 4; ++ci) {
    float4* buf = &Rs[cur][0];
    buf[d0] = st[0];                              // stage chunk ci
    buf[d1] = st[1];
    if (ci < 3) {                                 // prefetch chunk ci+1
      const float4* src = v1cs + ((size_t)(ci + 1) * T_ + t) * HW_;
      st[0] = src[soff[0]];
      st[1] = src[soff[1]];
    }
    __syncthreads();                              // buf[cur] ready
    if (compute_ok) {
#pragma unroll 1
      for (int r = r0; r < r1; ++r) {
        v2f q0lo[7], q0hi[7], q1lo[7], q1hi[7];
        const float4* q0row = &buf[(rbase + 13 + r) * RW_ + dj + 13];
#pragma unroll
        for (int s = 0; s < 7; ++s) {
          float4 qq = q0row[s];                   // q0 patch row (broadcast)
          q0lo[s] = (v2f){qq.x, qq.y};
          q0hi[s] = (v2f){qq.z, qq.w};
          float4 q2 = q0row[4 * RW_ + s];         // q1 patch row = +4 rows
          q1lo[s] = (v2f){q2.x, q2.y};
          q1hi[s] = (v2f){q2.z, q2.w};
        }
        const float4* crow = &buf[(rbase + la + r) * RW_ + dj + bs];
#pragma unroll
        for (int y = 0; y < 20; ++y) {
          float4 vv4 = crow[y];                   // shared by q0 AND q1
          v2f vlo = (v2f){vv4.x, vv4.y}, vhi = (v2f){vv4.z, vv4.w};
          const int s_lo = (y > 13) ? (y - 13) : 0;
          const int s_hi = (y < 6) ? y : 6;
#pragma unroll
          for (int s = s_lo; s <= s_hi; ++s) {
            int j = y - s;
            acc0[j] = VFMA(q0lo[s], vlo, acc0[j]);
            acc0[j] = VFMA(q0hi[s], vhi, acc0[j]);
            acc1[j] = VFMA(q1lo[s], vlo, acc1[j]);
            acc1[j] = VFMA(q1hi[s], vhi, acc1[j]);
          }
        }
      }
    }
    __syncthreads();                              // all reads done before re-stage
    cur ^= 1;
  }
  if (compute_ok) {
    float* outB = (rset && !use_atomic) ? distB : distG;
    const int q0q = ((qi_p >> 2) << 5) + (qj >> 2);
    if (la >= a_lo0 && la <= 26 && !(use_atomic && bdup)) {
      float* out = outB + ((size_t)t * NQ_ + q0q) * NC_ + la * 27 + bs;
      if (use_atomic) {
#pragma unroll
        for (int j = 0; j < 14; ++j) atomicAdd(out + j, acc0[j].x + acc0[j].y);
      } else {
#pragma unroll
        for (int j = 0; j < 14; ++j) out[j] = acc0[j].x + acc0[j].y;
      }
    }
    const int a1 = la - 4;
    if (a1 >= a_lo1 && a1 <= 26 && !(use_atomic && bdup)) {
      float* out = outB + ((size_t)t * NQ_ + (q0q + 32)) * NC_ + a1 * 27 + bs;
      if (use_atomic) {
#pragma unroll
        for (int j = 0; j < 14; ++j) atomicAdd(out + j, acc1[j].x + acc1[j].y);
      } else {
#pragma unroll
        for (int j = 0; j < 14; ++j) out[j] = acc1[j].x + acc1[j].y;
      }
    }
  }
}

// ---------------- select: 2-level radix top-100, wave-primitive scans -------
__global__ __launch_bounds__(256) void select_kernel(
    const float* __restrict__ distA, const float* __restrict__ distB, int dual,
    int* __restrict__ sel_n, float* __restrict__ sel_w,
    float* __restrict__ wsum_out) {
  __shared__ float dist[NC_];
  __shared__ unsigned int ukey[NC_];
  __shared__ float redf[4];
  __shared__ unsigned int hist[256];
  __shared__ int lk[LCAP_];
  __shared__ unsigned int lkey[LCAP_];
  __shared__ unsigned int scal[6];   // 0=beta 1=run 2=cursor 3=listlen 4=beta2 5=run2

  const int tid = threadIdx.x;
  const int lane = tid & 63, wid = tid >> 6;
  const int q = blockIdx.x, t = blockIdx.y;
  const int qi = (q >> 5) * S0_, qj = (q & 31) * S0_;
  const int a_lo = max(13 - qi, 0), b_lo = max(13 - qj, 0);
  const size_t base = ((size_t)t * NQ_ + q) * NC_;

  for (int h = tid; h < 256; h += 256) hist[h] = 0;
  if (tid == 0) { scal[2] = 0; scal[3] = 0; }
  float lmax = -INFINITY;
  for (int k = tid; k < NC_; k += 256) {
    int aa = k / 27, bb = k - aa * 27;
    int kk = max(aa, a_lo) * 27 + max(bb, b_lo);
    float d = distA[base + kk];
    if (dual) d += distB[base + kk];
    dist[k] = d;
    unsigned int u = __float_as_uint(d);
    ukey[k] = u ^ (((unsigned int)((int)u >> 31)) | 0x80000000u);
    lmax = fmaxf(lmax, d);
  }
#pragma unroll
  for (int off = 32; off > 0; off >>= 1)
    lmax = fmaxf(lmax, __shfl_down(lmax, off, 64));
  if (lane == 0) redf[wid] = lmax;
  __syncthreads();                                             // B1
  const float dmax = fmaxf(fmaxf(redf[0], redf[1]), fmaxf(redf[2], redf[3]));
  for (int k = tid; k < NC_; k += 256) atomicAdd(&hist[ukey[k] >> 24], 1u);
  __syncthreads();                                             // B2
  if (wid == 0) {
    int s4 = (int)(hist[lane * 4] + hist[lane * 4 + 1] + hist[lane * 4 + 2] + hist[lane * 4 + 3]);
    int s = s4;
#pragma unroll
    for (int off = 1; off < 64; off <<= 1) {
      int o = __shfl_down(s, off, 64);
      if (lane + off < 64) s += o;
    }
    int above = s - s4;
    if (above < KS_ && s >= KS_) {
      int run = above;
#pragma unroll
      for (int bb = 3; bb >= 0; --bb) {
        int h = (int)hist[lane * 4 + bb];
        if (run + h >= KS_) { scal[0] = (unsigned int)(lane * 4 + bb); scal[1] = (unsigned int)run; break; }
        run += h;
      }
    }
  }
  __syncthreads();                                             // B3
  const unsigned int beta = scal[0];
  const int run = (int)scal[1];
  for (int h = tid; h < 256; h += 256) hist[h] = 0;
  __syncthreads();                                             // B4
  for (int k = tid; k < NC_; k += 256)
    if ((ukey[k] >> 24) == beta) atomicAdd(&hist[(ukey[k] >> 16) & 0xFFu], 1u);
  __syncthreads();                                             // B5
  if (wid == 0) {
    int s4 = (int)(hist[lane * 4] + hist[lane * 4 + 1] + hist[lane * 4 + 2] + hist[lane * 4 + 3]);
    int s = s4;
#pragma unroll
    for (int off = 1; off < 64; off <<= 1) {
      int o = __shfl_down(s, off, 64);
      if (lane + off < 64) s += o;
    }
    int above = run + s - s4;
    if (above < KS_ && run + s >= KS_) {
      int r2 = above;
#pragma unroll
      for (int bb = 3; bb >= 0; --bb) {
        int h = (int)hist[lane * 4 + bb];
        if (r2 + h >= KS_) { scal[4] = (unsigned int)(lane * 4 + bb); scal[5] = (unsigned int)r2; break; }
        r2 += h;
      }
    }
  }
  __syncthreads();                                             // B6
  const unsigned int beta2 = scal[4];
  const int run2 = (int)scal[5];
  const size_t outb = ((size_t)t * NQ_ + q) * KS_;
  float lsum = 0.f;
  for (int k = tid; k < NC_; k += 256) {
    unsigned int key = ukey[k];
    unsigned int bin = key >> 24;
    bool sel = false, bdry = false;
    if (bin > beta) sel = true;
    else if (bin == beta) {
      unsigned int b2 = (key >> 16) & 0xFFu;
      if (b2 > beta2) sel = true;
      else if (b2 == beta2) bdry = true;
    }
    if (sel) {
      unsigned int slot = atomicAdd(&scal[2], 1u);
      int aa = k / 27, bb = k - aa * 27;
      int ni = min(max(qi + aa - 13, 0), H_ - 1);
      int nj = min(max(qj + bb - 13, 0), W_ - 1);
      float wv = __expf(SCALE_ * (dist[k] - dmax));
      sel_n[outb + slot] = (ni << 7) | nj;
      sel_w[outb + slot] = wv;
      lsum += wv;
    } else if (bdry) {
      unsigned int pos = atomicAdd(&scal[3], 1u);
      if (pos < LCAP_) { lk[pos] = k; lkey[pos] = key; }
    }
  }
  __syncthreads();                                             // B7
  const int L = min((int)scal[3], LCAP_);
  for (int i = tid; i < L; i += 256) {
    unsigned int key = lkey[i];
    int k = lk[i];
    int cnt = run2;
    for (int m = 0; m < L; ++m)
      cnt += (int)((lkey[m] > key) || (lkey[m] == key && lk[m] < k));
    if (cnt < KS_) {
      unsigned int slot = atomicAdd(&scal[2], 1u);
      int aa = k / 27, bb = k - aa * 27;
      int ni = min(max(qi + aa - 13, 0), H_ - 1);
      int nj = min(max(qj + bb - 13, 0), W_ - 1);
      float wv = __expf(SCALE_ * (dist[k] - dmax));
      sel_n[outb + slot] = (ni << 7) | nj;
      sel_w[outb + slot] = wv;
      lsum += wv;
    }
  }
#pragma unroll
  for (int off = 32; off > 0; off >>= 1) lsum += __shfl_down(lsum, off, 64);
  __syncthreads();                                             // B8
  if (lane == 0) redf[wid] = lsum;
  __syncthreads();                                             // B9
  if (tid == 0) wsum_out[t * NQ_ + q] = (redf[0] + redf[1]) + (redf[2] + redf[3]);
}

// ---------------- weighted aggregation + fold (4x4-tile LDS region) ---------
// 1024 threads = 16 waves = 16 queries sharing a 45x45 float4 region.
// L2 gather traffic (2.7 GB) -> coalesced staging (~33 MB) + LDS reads.
__global__ __launch_bounds__(1024) void agg_kernel(
    const float4* __restrict__ v2cs, const int* __restrict__ sel_n,
    const float* __restrict__ sel_w, const float* __restrict__ wsum,
    float* __restrict__ Y) {
  __shared__ float4 Rs[RW_ * RW_];
  __shared__ int s_off[16][KS_];
  __shared__ float s_w[16][KS_];
  const int tid = threadIdx.x;
  const int t = blockIdx.y;
  const int qi0 = (blockIdx.x >> 3) * 16, qj0 = (blockIdx.x & 7) * 16;
  const int w = tid >> 6, lane = tid & 63;
  const int di = (w >> 2) * 4, dj = (w & 3) * 4;
  const int qi = qi0 + di, qj = qj0 + dj;
  const int q = ((qi >> 2) << 5) + (qj >> 2);
  const size_t base = ((size_t)t * NQ_ + q) * KS_;
  const float inv = 1.0f / wsum[t * NQ_ + q];
  for (int k = lane; k < KS_; k += 64) {
    int n = sel_n[base + k];
    int ni = n >> 7, nj = n & 127;
    s_off[w][k] = (ni - qi0 + 13) * RW_ + (nj - qj0 + 13);
    s_w[w][k] = sel_w[base + k] * inv;
  }
  const int r = lane / 7, s = lane - r * 7;    // valid for lane < 49
  const int myo = r * RW_ + s;
  const int oi = min(qi + r, H_ - 1), oj = min(qj + s, W_ - 1);
#pragma unroll 1
  for (int cc = 0; cc < 4; ++cc) {
    __syncthreads();
    const float4* src = v2cs + ((size_t)cc * T_ + t) * HW_;
    for (int p = tid; p < RW_ * RW_; p += 1024) {
      int uu = p / RW_, vv = p - uu * RW_;
      int row = min(max(qi0 - 13 + uu, 0), H_ - 1);
      int col = min(max(qj0 - 13 + vv, 0), W_ - 1);
      Rs[p] = src[row * W_ + col];
    }
    __syncthreads();
    if (lane < 49) {
      float4 acc = make_float4(0.f, 0.f, 0.f, 0.f);
#pragma unroll 4
      for (int k = 0; k < KS_; ++k) {
        float wv = s_w[w][k];
        float4 v = Rs[s_off[w][k] + myo];
        acc.x = fmaf(wv, v.x, acc.x);
        acc.y = fmaf(wv, v.y, acc.y);
        acc.z = fmaf(wv, v.z, acc.z);
        acc.w = fmaf(wv, v.w, acc.w);
      }
      float* yb = Y + (((size_t)t * CI_ + cc * 4) * H_ + oi) * W_ + oj;
      atomicAdd(yb, acc.x);
      atomicAdd(yb + HW_, acc.y);
      atomicAdd(yb + 2 * HW_, acc.z);
      atomicAdd(yb + 3 * HW_, acc.w);
    }
  }
}

// ---------------- normalize by analytic fold counts -------------------------
__device__ __forceinline__ int cov_axis(int x) {
  int c = 0;
#pragma unroll
  for (int r = 0; r < 7; ++r) {
    if (x < H_ - 1) {
      int qb = x - r;
      c += (qb >= 0 && (qb & 3) == 0) ? 1 : 0;
    } else {
      c += (r >= 3) ? 1 : 0;
    }
  }
  return c;
}

__global__ void norm_kernel(float* __restrict__ Y) {
  int idx = blockIdx.x * blockDim.x + threadIdx.x;
  if (idx >= T_ * CI_ * HW_) return;
  int p = idx & (HW_ - 1);
  float z = (float)(cov_axis(p >> 7) * cov_axis(p & 127));
  Y[idx] /= z;
}

extern "C" void kernel_launch(void* const* d_in, const int* in_sizes, int n_in,
                              void* d_out, int out_size, void* d_ws, size_t ws_size,
                              hipStream_t stream) {
  const float* vid     = (const float*)d_in[0];
  const float* g_w     = (const float*)d_in[1];
  const float* g_b     = (const float*)d_in[2];
  const float* theta_w = (const float*)d_in[3];
  const float* theta_b = (const float*)d_in[4];
  float* Y = (float*)d_out;

  // workspace (floats): v1cs | v2cs | distG | sel_n | sel_w | wsum | distB
  float* v1cs  = (float*)d_ws;
  float* v2cs  = v1cs + (size_t)4 * T_ * HW_ * 4;              // 1048576
  float* distG = v2cs + (size_t)4 * T_ * HW_ * 4;              // 1048576
  int*   sel_n = (int*)(distG + (size_t)T_ * NQ_ * NC_);       // 2985984
  float* sel_w = (float*)(sel_n + (size_t)T_ * NQ_ * KS_);     // 409600
  float* wsumv = sel_w + (size_t)T_ * NQ_ * KS_;               // 409600
  float* distB = wsumv + (size_t)T_ * NQ_;                     // 4096

  // split mode needs the second partial-dist buffer (+~12 MB); gate on ws_size
  // (R5-R7 ran dual on this harness => normally taken).
  const size_t need_dual =
      ((size_t)4 * T_ * HW_ * 4 * 2 + (size_t)T_ * NQ_ * NC_ * 2 +
       (size_t)T_ * NQ_ * KS_ * 2 + (size_t)T_ * NQ_) * sizeof(float);
  const int dual = (ws_size >= need_dual) ? 1 : 0;

  hipMemsetAsync(Y, 0, (size_t)out_size * sizeof(float), stream);
  if (!dual)
    hipMemsetAsync(distG, 0, (size_t)T_ * NQ_ * NC_ * sizeof(float), stream);

  conv3x3_kernel<<<dim3(64, 4, T_), 128, 0, stream>>>(vid, g_w, g_b, (float4*)v1cs);
  conv1x1_kernel<<<dim3(HW_ / 256, T_, 4), 256, 0, stream>>>(vid, theta_w, theta_b, (float4*)v2cs);
  dist_kernel<<<dim3(64, T_), 1024, 0, stream>>>(
      (const float4*)v1cs, distG, distB, dual ? 0 : 1);
  select_kernel<<<dim3(NQ_, T_), 256, 0, stream>>>(distG, distB, dual, sel_n, sel_w, wsumv);
  agg_kernel<<<dim3(64, T_), 1024, 0, stream>>>((const float4*)v2cs, sel_n, sel_w, wsumv, Y);
  norm_kernel<<<(T_ * CI_ * HW_ + 255) / 256, 256, 0, stream>>>(Y);
}

// Round 9
// 259.094 us; speedup vs baseline: 1.4071x; 1.3369x over previous
//
#include <hip/hip_runtime.h>
#include <hip/hip_bf16.h>

#define T_ 4
#define C_ 64
#define H_ 128
#define W_ 128
#define CI_ 16
#define PS_ 7
#define NC_ 729       // 27*27 candidates per query
#define S0_ 4
#define KS_ 100
#define NQ_ 1024      // 32*32 queries per frame
#define SCALE_ 10.0f
#define HW_ (H_*W_)
#define RW_ 45        // 4x4-tile region dim (float4); 45%8=5 -> bank rotation
#define LCAP_ 768
#define CB_ 8         // conv3x3 channel batch (24 dwordx4 in flight)

typedef float v2f __attribute__((ext_vector_type(2)));
#if __has_builtin(__builtin_elementwise_fma)
#define VFMA(a, b, c) __builtin_elementwise_fma((a), (b), (c))
#else
#define VFMA(a, b, c) ((a) * (b) + (c))
#endif

// ---------------- conv 3x3, 64->16, BRANCH-FREE batched loads ---------------
__device__ __forceinline__ float4 colfix(float4 r, bool loB, bool hiB) {
  float4 o;
  o.x = loB ? 0.f : (hiB ? r.y : r.x);
  o.y = loB ? r.x : (hiB ? r.z : r.y);
  o.z = loB ? r.y : (hiB ? r.w : r.z);
  o.w = loB ? r.z : (hiB ? 0.f : r.w);
  return o;
}

__global__ __launch_bounds__(128, 1) void conv3x3_kernel(
    const float* __restrict__ vid, const float* __restrict__ gw,
    const float* __restrict__ gb, float4* __restrict__ v1cs) {
  __shared__ float wls[C_ * 9 * 4];   // [c][k][co]
  const int tid = threadIdx.x;
  const int g = blockIdx.y, t = blockIdx.z;
  for (int m = tid; m < C_ * 9 * 4; m += 128) {
    int co = m & 3, ck = m >> 2;
    wls[m] = gw[((size_t)(g * 4 + co) * C_) * 9 + ck];
  }
  __syncthreads();
  const int ti0 = (blockIdx.x >> 3) * 16, tj0 = (blockIdx.x & 7) * 16;
  const int u = tid >> 3, v = tid & 7;   // 16 rows x 8 col-pairs
  const int i = ti0 + u, j0 = tj0 + 2 * v;
  const int c0 = j0 - 1;
  const int c0c = min(max(c0, 0), W_ - 4);
  const bool loB = (c0 < 0), hiB = (c0 > W_ - 4);
  const int rm1 = max(i - 1, 0), rp1 = min(i + 1, H_ - 1);
  const float mk0 = (i > 0) ? 1.f : 0.f;
  const float mk2 = (i < H_ - 1) ? 1.f : 0.f;
  const int o0 = rm1 * W_ + c0c, o1 = i * W_ + c0c, o2 = rp1 * W_ + c0c;

  float accA[4], accB[4];
#pragma unroll
  for (int co = 0; co < 4; ++co) { accA[co] = gb[g * 4 + co]; accB[co] = gb[g * 4 + co]; }

  const float* vb = vid + ((size_t)t * C_) * HW_;
#pragma unroll 1
  for (int cb = 0; cb < C_; cb += CB_) {
    float4 r[CB_][3];
#pragma unroll
    for (int c = 0; c < CB_; ++c) {       // 24 UNCONDITIONAL loads -> in flight
      const float* p = vb + (size_t)(cb + c) * HW_;
      r[c][0] = *(const float4*)(p + o0);
      r[c][1] = *(const float4*)(p + o1);
      r[c][2] = *(const float4*)(p + o2);
    }
#pragma unroll
    for (int c = 0; c < CB_; ++c) {
      float4 f0 = colfix(r[c][0], loB, hiB);
      float4 f1 = colfix(r[c][1], loB, hiB);
      float4 f2 = colfix(r[c][2], loB, hiB);
      f0.x *= mk0; f0.y *= mk0; f0.z *= mk0; f0.w *= mk0;
      f2.x *= mk2; f2.y *= mk2; f2.z *= mk2; f2.w *= mk2;
      const float* wc = &wls[(cb + c) * 36];
      float e0[4] = {f0.x, f0.y, f0.z, f0.w};
      float e1[4] = {f1.x, f1.y, f1.z, f1.w};
      float e2[4] = {f2.x, f2.y, f2.z, f2.w};
#pragma unroll
      for (int kj = 0; kj < 3; ++kj) {
#pragma unroll
        for (int co = 0; co < 4; ++co) {
          accA[co] = fmaf(wc[(0 * 3 + kj) * 4 + co], e0[kj],     accA[co]);
          accB[co] = fmaf(wc[(0 * 3 + kj) * 4 + co], e0[kj + 1], accB[co]);
          accA[co] = fmaf(wc[(1 * 3 + kj) * 4 + co], e1[kj],     accA[co]);
          accB[co] = fmaf(wc[(1 * 3 + kj) * 4 + co], e1[kj + 1], accB[co]);
          accA[co] = fmaf(wc[(2 * 3 + kj) * 4 + co], e2[kj],     accA[co]);
          accB[co] = fmaf(wc[(2 * 3 + kj) * 4 + co], e2[kj + 1], accB[co]);
        }
      }
    }
  }
  const size_t o = ((size_t)g * T_ + t) * HW_ + i * W_ + j0;
  v1cs[o]     = make_float4(accA[0], accA[1], accA[2], accA[3]);
  v1cs[o + 1] = make_float4(accB[0], accB[1], accB[2], accB[3]);
}

// ---------------- conv 1x1, 64->16, chunk-major float4 output ----------------
__global__ __launch_bounds__(256, 1) void conv1x1_kernel(
    const float* __restrict__ vid, const float* __restrict__ tw,
    const float* __restrict__ tb, float4* __restrict__ v2cs) {
  __shared__ float w[C_ * 4];
  const int t = blockIdx.y, cc = blockIdx.z;
  for (int m = threadIdx.x; m < C_ * 4; m += 256) {
    int o = m & 3, c = m >> 2;
    w[m] = tw[(cc * 4 + o) * C_ + c];
  }
  __syncthreads();
  const int pix = blockIdx.x * 256 + threadIdx.x;
  float acc[4];
#pragma unroll
  for (int o = 0; o < 4; ++o) acc[o] = tb[cc * 4 + o];
  const float* vb = vid + ((size_t)t * C_) * HW_ + pix;
#pragma unroll 1
  for (int c0 = 0; c0 < C_; c0 += 16) {
    float x[16];
#pragma unroll
    for (int uu = 0; uu < 16; ++uu) x[uu] = vb[(size_t)(c0 + uu) * HW_];
#pragma unroll
    for (int uu = 0; uu < 16; ++uu)
#pragma unroll
      for (int o = 0; o < 4; ++o)
        acc[o] = fmaf(w[(c0 + uu) * 4 + o], x[uu], acc[o]);
  }
  v2cs[((size_t)cc * T_ + t) * HW_ + pix] = make_float4(acc[0], acc[1], acc[2], acc[3]);
}

// ---------------- dists: query-PAIR per wave (qi, qi+4 share candidate rows) -
// EXACT R3 configuration (harness-verified: 71.7us, VGPR 84, no spill).
// Lane la = lane>>1 in [0,30]: serves q0 at a=la and q1(=q0+4 rows) at a=la-4;
// both read the SAME Rs rows, halving per-query LDS reads vs the R0 form.
// 512 threads = 8 waves = 8 query pairs = 16 queries per 16x16 region.
// launch_bounds (512,2): yields a 128-VGPR budget on this stack (R3/R5
// measured 80-84, no scratch). Do NOT use 1024-thr blocks here: the backend
// pins them to a 64-VGPR budget regardless of waves_per_eu/LDS padding
// (R4/R6/R7/R8: VGPR=64, 240-475MB scratch, 143-175us).
__global__ __launch_bounds__(512, 2) void dist_kernel(
    const float4* __restrict__ v1cs, float* __restrict__ distG) {
  __shared__ float4 Rs[2][2048];                 // 2 x 45*45 (padded) = 64 KiB
  const int tid = threadIdx.x;
  const int t = blockIdx.y;
  const int qi0 = (blockIdx.x >> 3) * 16, qj0 = (blockIdx.x & 7) * 16;
  const int w = tid >> 6, lane = tid & 63;
  const int pr = w >> 2, dj = (w & 3) * 4;       // pair-row {0,1}, col-tile
  const int rbase = 8 * pr;
  const int qi_p = qi0 + rbase;                  // q0 pixel row; q1 = qi_p+4
  const int qj = qj0 + dj;
  const int la = lane >> 1, bg = lane & 1;
  const int b_lo = max(13 - qj, 0);
  const int bs = bg ? 13 : b_lo;
  const int a_lo0 = max(13 - qi_p, 0);
  const int a_lo1 = max(9 - qi_p, 0);
  const bool compute_ok = (la < 31);

  // staging: 4 float4 per thread per chunk; source clamped, dest linear
  int soff[4];
#pragma unroll
  for (int k = 0; k < 4; ++k) {
    int p = min(tid + 512 * k, RW_ * RW_ - 1);
    int uu = p / RW_, vv = p - uu * RW_;
    int row = min(max(qi0 - 13 + uu, 0), H_ - 1);
    int col = min(max(qj0 - 13 + vv, 0), W_ - 1);
    soff[k] = row * W_ + col;
  }

  v2f acc0[14], acc1[14];
#pragma unroll
  for (int j = 0; j < 14; ++j) { acc0[j] = (v2f){0.f, 0.f}; acc1[j] = (v2f){0.f, 0.f}; }

  float4 st[4];
  {
    const float4* src = v1cs + ((size_t)0 * T_ + t) * HW_;
#pragma unroll
    for (int k = 0; k < 4; ++k) st[k] = src[soff[k]];
  }
  int cur = 0;
#pragma unroll 1
  for (int cc = 0; cc < 4; ++cc) {
    float4* buf = &Rs[cur][0];
#pragma unroll
    for (int k = 0; k < 4; ++k) buf[tid + 512 * k] = st[k];   // stage chunk cc
    if (cc < 3) {                                             // prefetch cc+1
      const float4* src = v1cs + ((size_t)(cc + 1) * T_ + t) * HW_;
#pragma unroll
      for (int k = 0; k < 4; ++k) st[k] = src[soff[k]];
    }
    __syncthreads();                                          // buf[cur] ready
    if (compute_ok) {
#pragma unroll 1
      for (int r = 0; r < 7; ++r) {
        v2f q0lo[7], q0hi[7], q1lo[7], q1hi[7];
        const float4* q0row = &buf[(rbase + 13 + r) * RW_ + dj + 13];
#pragma unroll
        for (int s = 0; s < 7; ++s) {
          float4 qq = q0row[s];                 // q0 patch row (broadcast)
          q0lo[s] = (v2f){qq.x, qq.y};
          q0hi[s] = (v2f){qq.z, qq.w};
          float4 q2 = q0row[4 * RW_ + s];       // q1 patch row = +4 rows
          q1lo[s] = (v2f){q2.x, q2.y};
          q1hi[s] = (v2f){q2.z, q2.w};
        }
        const float4* crow = &buf[(rbase + la + r) * RW_ + dj + bs];
#pragma unroll
        for (int y = 0; y < 20; ++y) {
          float4 vv4 = crow[y];                 // shared by q0 AND q1
          v2f vlo = (v2f){vv4.x, vv4.y}, vhi = (v2f){vv4.z, vv4.w};
          const int s_lo = (y > 13) ? (y - 13) : 0;
          const int s_hi = (y < 6) ? y : 6;
#pragma unroll
          for (int s = s_lo; s <= s_hi; ++s) {
            int j = y - s;
            acc0[j] = VFMA(q0lo[s], vlo, acc0[j]);
            acc0[j] = VFMA(q0hi[s], vhi, acc0[j]);
            acc1[j] = VFMA(q1lo[s], vlo, acc1[j]);
            acc1[j] = VFMA(q1hi[s], vhi, acc1[j]);
          }
        }
      }
    }
    cur ^= 1;
  }
  if (compute_ok) {
    const int q0q = ((qi_p >> 2) << 5) + (qj >> 2);
    if (la >= a_lo0 && la <= 26) {
      float* out = distG + ((size_t)t * NQ_ + q0q) * NC_ + la * 27 + bs;
#pragma unroll
      for (int j = 0; j < 14; ++j) out[j] = acc0[j].x + acc0[j].y;
    }
    const int a1 = la - 4;
    if (a1 >= a_lo1 && a1 <= 26) {
      float* out = distG + ((size_t)t * NQ_ + (q0q + 32)) * NC_ + a1 * 27 + bs;
#pragma unroll
      for (int j = 0; j < 14; ++j) out[j] = acc1[j].x + acc1[j].y;
    }
  }
}

// ---------------- select: 2-level radix top-100, wave-primitive scans -------
__global__ __launch_bounds__(256) void select_kernel(
    const float* __restrict__ distG, int* __restrict__ sel_n,
    float* __restrict__ sel_w, float* __restrict__ wsum_out) {
  __shared__ float dist[NC_];
  __shared__ unsigned int ukey[NC_];
  __shared__ float redf[4];
  __shared__ unsigned int hist[256];
  __shared__ int lk[LCAP_];
  __shared__ unsigned int lkey[LCAP_];
  __shared__ unsigned int scal[6];   // 0=beta 1=run 2=cursor 3=listlen 4=beta2 5=run2

  const int tid = threadIdx.x;
  const int lane = tid & 63, wid = tid >> 6;
  const int q = blockIdx.x, t = blockIdx.y;
  const int qi = (q >> 5) * S0_, qj = (q & 31) * S0_;
  const int a_lo = max(13 - qi, 0), b_lo = max(13 - qj, 0);
  const size_t base = ((size_t)t * NQ_ + q) * NC_;

  for (int h = tid; h < 256; h += 256) hist[h] = 0;
  if (tid == 0) { scal[2] = 0; scal[3] = 0; }
  float lmax = -INFINITY;
  for (int k = tid; k < NC_; k += 256) {
    int aa = k / 27, bb = k - aa * 27;
    int kk = max(aa, a_lo) * 27 + max(bb, b_lo);
    float d = distG[base + kk];
    dist[k] = d;
    unsigned int u = __float_as_uint(d);
    ukey[k] = u ^ (((unsigned int)((int)u >> 31)) | 0x80000000u);
    lmax = fmaxf(lmax, d);
  }
#pragma unroll
  for (int off = 32; off > 0; off >>= 1)
    lmax = fmaxf(lmax, __shfl_down(lmax, off, 64));
  if (lane == 0) redf[wid] = lmax;
  __syncthreads();                                             // B1
  const float dmax = fmaxf(fmaxf(redf[0], redf[1]), fmaxf(redf[2], redf[3]));
  for (int k = tid; k < NC_; k += 256) atomicAdd(&hist[ukey[k] >> 24], 1u);
  __syncthreads();                                             // B2
  if (wid == 0) {
    int s4 = (int)(hist[lane * 4] + hist[lane * 4 + 1] + hist[lane * 4 + 2] + hist[lane * 4 + 3]);
    int s = s4;
#pragma unroll
    for (int off = 1; off < 64; off <<= 1) {
      int o = __shfl_down(s, off, 64);
      if (lane + off < 64) s += o;
    }
    int above = s - s4;
    if (above < KS_ && s >= KS_) {
      int run = above;
#pragma unroll
      for (int bb = 3; bb >= 0; --bb) {
        int h = (int)hist[lane * 4 + bb];
        if (run + h >= KS_) { scal[0] = (unsigned int)(lane * 4 + bb); scal[1] = (unsigned int)run; break; }
        run += h;
      }
    }
  }
  __syncthreads();                                             // B3
  const unsigned int beta = scal[0];
  const int run = (int)scal[1];
  for (int h = tid; h < 256; h += 256) hist[h] = 0;
  __syncthreads();                                             // B4
  for (int k = tid; k < NC_; k += 256)
    if ((ukey[k] >> 24) == beta) atomicAdd(&hist[(ukey[k] >> 16) & 0xFFu], 1u);
  __syncthreads();                                             // B5
  if (wid == 0) {
    int s4 = (int)(hist[lane * 4] + hist[lane * 4 + 1] + hist[lane * 4 + 2] + hist[lane * 4 + 3]);
    int s = s4;
#pragma unroll
    for (int off = 1; off < 64; off <<= 1) {
      int o = __shfl_down(s, off, 64);
      if (lane + off < 64) s += o;
    }
    int above = run + s - s4;
    if (above < KS_ && run + s >= KS_) {
      int r2 = above;
#pragma unroll
      for (int bb = 3; bb >= 0; --bb) {
        int h = (int)hist[lane * 4 + bb];
        if (r2 + h >= KS_) { scal[4] = (unsigned int)(lane * 4 + bb); scal[5] = (unsigned int)r2; break; }
        r2 += h;
      }
    }
  }
  __syncthreads();                                             // B6
  const unsigned int beta2 = scal[4];
  const int run2 = (int)scal[5];
  const size_t outb = ((size_t)t * NQ_ + q) * KS_;
  float lsum = 0.f;
  for (int k = tid; k < NC_; k += 256) {
    unsigned int key = ukey[k];
    unsigned int bin = key >> 24;
    bool sel = false, bdry = false;
    if (bin > beta) sel = true;
    else if (bin == beta) {
      unsigned int b2 = (key >> 16) & 0xFFu;
      if (b2 > beta2) sel = true;
      else if (b2 == beta2) bdry = true;
    }
    if (sel) {
      unsigned int slot = atomicAdd(&scal[2], 1u);
      int aa = k / 27, bb = k - aa * 27;
      int ni = min(max(qi + aa - 13, 0), H_ - 1);
      int nj = min(max(qj + bb - 13, 0), W_ - 1);
      float wv = __expf(SCALE_ * (dist[k] - dmax));
      sel_n[outb + slot] = (ni << 7) | nj;
      sel_w[outb + slot] = wv;
      lsum += wv;
    } else if (bdry) {
      unsigned int pos = atomicAdd(&scal[3], 1u);
      if (pos < LCAP_) { lk[pos] = k; lkey[pos] = key; }
    }
  }
  __syncthreads();                                             // B7
  const int L = min((int)scal[3], LCAP_);
  for (int i = tid; i < L; i += 256) {
    unsigned int key = lkey[i];
    int k = lk[i];
    int cnt = run2;
    for (int m = 0; m < L; ++m)
      cnt += (int)((lkey[m] > key) || (lkey[m] == key && lk[m] < k));
    if (cnt < KS_) {
      unsigned int slot = atomicAdd(&scal[2], 1u);
      int aa = k / 27, bb = k - aa * 27;
      int ni = min(max(qi + aa - 13, 0), H_ - 1);
      int nj = min(max(qj + bb - 13, 0), W_ - 1);
      float wv = __expf(SCALE_ * (dist[k] - dmax));
      sel_n[outb + slot] = (ni << 7) | nj;
      sel_w[outb + slot] = wv;
      lsum += wv;
    }
  }
#pragma unroll
  for (int off = 32; off > 0; off >>= 1) lsum += __shfl_down(lsum, off, 64);
  __syncthreads();                                             // B8
  if (lane == 0) redf[wid] = lsum;
  __syncthreads();                                             // B9
  if (tid == 0) wsum_out[t * NQ_ + q] = (redf[0] + redf[1]) + (redf[2] + redf[3]);
}

// ---------------- fold-count helper (analytic normalization) ----------------
__device__ __forceinline__ int cov_axis(int x) {
  int c = 0;
#pragma unroll
  for (int r = 0; r < 7; ++r) {
    if (x < H_ - 1) {
      int qb = x - r;
      c += (qb >= 0 && (qb & 3) == 0) ? 1 : 0;
    } else {
      c += (r >= 3) ? 1 : 0;
    }
  }
  return c;
}

// ---------------- weighted aggregation + fold + FUSED normalization ---------
// 1024 threads = 16 waves = 16 queries sharing a 45x45 float4 region.
// Normalization folded in: each contribution to pixel (oi,oj) is pre-scaled
// by 1/Z(oi,oj) (Z analytic per pixel; division distributes over the atomic
// sum) -> norm_kernel deleted: saves a launch + 8 MB of Y read/write.
__global__ __launch_bounds__(1024) void agg_kernel(
    const float4* __restrict__ v2cs, const int* __restrict__ sel_n,
    const float* __restrict__ sel_w, const float* __restrict__ wsum,
    float* __restrict__ Y) {
  __shared__ float4 Rs[RW_ * RW_];
  __shared__ int s_off[16][KS_];
  __shared__ float s_w[16][KS_];
  const int tid = threadIdx.x;
  const int t = blockIdx.y;
  const int qi0 = (blockIdx.x >> 3) * 16, qj0 = (blockIdx.x & 7) * 16;
  const int w = tid >> 6, lane = tid & 63;
  const int di = (w >> 2) * 4, dj = (w & 3) * 4;
  const int qi = qi0 + di, qj = qj0 + dj;
  const int q = ((qi >> 2) << 5) + (qj >> 2);
  const size_t base = ((size_t)t * NQ_ + q) * KS_;
  const float inv = 1.0f / wsum[t * NQ_ + q];
  for (int k = lane; k < KS_; k += 64) {
    int n = sel_n[base + k];
    int ni = n >> 7, nj = n & 127;
    s_off[w][k] = (ni - qi0 + 13) * RW_ + (nj - qj0 + 13);
    s_w[w][k] = sel_w[base + k] * inv;
  }
  const int r = lane / 7, s = lane - r * 7;    // valid for lane < 49
  const int myo = r * RW_ + s;
  const int oi = min(qi + r, H_ - 1), oj = min(qj + s, W_ - 1);
  const float invZ = 1.0f / (float)(cov_axis(oi) * cov_axis(oj));
#pragma unroll 1
  for (int cc = 0; cc < 4; ++cc) {
    __syncthreads();
    const float4* src = v2cs + ((size_t)cc * T_ + t) * HW_;
    for (int p = tid; p < RW_ * RW_; p += 1024) {
      int uu = p / RW_, vv = p - uu * RW_;
      int row = min(max(qi0 - 13 + uu, 0), H_ - 1);
      int col = min(max(qj0 - 13 + vv, 0), W_ - 1);
      Rs[p] = src[row * W_ + col];
    }
    __syncthreads();
    if (lane < 49) {
      float4 acc = make_float4(0.f, 0.f, 0.f, 0.f);
#pragma unroll 4
      for (int k = 0; k < KS_; ++k) {
        float wv = s_w[w][k];
        float4 v = Rs[s_off[w][k] + myo];
        acc.x = fmaf(wv, v.x, acc.x);
        acc.y = fmaf(wv, v.y, acc.y);
        acc.z = fmaf(wv, v.z, acc.z);
        acc.w = fmaf(wv, v.w, acc.w);
      }
      float* yb = Y + (((size_t)t * CI_ + cc * 4) * H_ + oi) * W_ + oj;
      atomicAdd(yb, acc.x * invZ);
      atomicAdd(yb + HW_, acc.y * invZ);
      atomicAdd(yb + 2 * HW_, acc.z * invZ);
      atomicAdd(yb + 3 * HW_, acc.w * invZ);
    }
  }
}

extern "C" void kernel_launch(void* const* d_in, const int* in_sizes, int n_in,
                              void* d_out, int out_size, void* d_ws, size_t ws_size,
                              hipStream_t stream) {
  const float* vid     = (const float*)d_in[0];
  const float* g_w     = (const float*)d_in[1];
  const float* g_b     = (const float*)d_in[2];
  const float* theta_w = (const float*)d_in[3];
  const float* theta_b = (const float*)d_in[4];
  float* Y = (float*)d_out;

  // workspace (floats): v1cs | v2cs | distG | sel_n | sel_w | wsum  (~24 MB)
  float* v1cs  = (float*)d_ws;
  float* v2cs  = v1cs + (size_t)4 * T_ * HW_ * 4;              // 1048576
  float* distG = v2cs + (size_t)4 * T_ * HW_ * 4;              // 1048576
  int*   sel_n = (int*)(distG + (size_t)T_ * NQ_ * NC_);       // 2985984
  float* sel_w = (float*)(sel_n + (size_t)T_ * NQ_ * KS_);     // 409600
  float* wsumv = sel_w + (size_t)T_ * NQ_ * KS_;               // 409600

  hipMemsetAsync(Y, 0, (size_t)out_size * sizeof(float), stream);

  conv3x3_kernel<<<dim3(64, 4, T_), 128, 0, stream>>>(vid, g_w, g_b, (float4*)v1cs);
  conv1x1_kernel<<<dim3(HW_ / 256, T_, 4), 256, 0, stream>>>(vid, theta_w, theta_b, (float4*)v2cs);
  dist_kernel<<<dim3(64, T_), 512, 0, stream>>>((const float4*)v1cs, distG);
  select_kernel<<<dim3(NQ_, T_), 256, 0, stream>>>(distG, sel_n, sel_w, wsumv);
  agg_kernel<<<dim3(64, T_), 1024, 0, stream>>>((const float4*)v2cs, sel_n, sel_w, wsumv, Y);
}

// Round 10
// 258.263 us; speedup vs baseline: 1.4117x; 1.0032x over previous
//
#include <hip/hip_runtime.h>
#include <hip/hip_bf16.h>

#define T_ 4
#define C_ 64
#define H_ 128
#define W_ 128
#define CI_ 16
#define PS_ 7
#define NC_ 729       // 27*27 candidates per query
#define S0_ 4
#define KS_ 100
#define NQ_ 1024      // 32*32 queries per frame
#define SCALE_ 10.0f
#define HW_ (H_*W_)
#define RW_ 45        // 4x4-tile region dim (float4); 45%8=5 -> bank rotation
#define LCAP_ 768
#define CB_ 8         // conv3x3 channel batch (24 dwordx4 in flight)

typedef float v2f __attribute__((ext_vector_type(2)));
#if __has_builtin(__builtin_elementwise_fma)
#define VFMA(a, b, c) __builtin_elementwise_fma((a), (b), (c))
#else
#define VFMA(a, b, c) ((a) * (b) + (c))
#endif

// ------- FUSED conv 3x3 + conv 1x1 (64->16 each), shared vid streaming ------
// Both convs read the same 67 MB of vid; the 3x3 kernel's center-row values
// e1[1], e1[2] ARE vid[t,c,i,j0], vid[t,c,i,j0+1] (colfix boundary-exact,
// row masks only touch rows i+-1) -> accumulate theta dot-products in the
// same channel loop. Block (tile,g,t) emits BOTH v1cs and v2cs channels
// 4g..4g+3. Kills the conv1x1 kernel: -67 MB vid re-read, -1 launch.
__device__ __forceinline__ float4 colfix(float4 r, bool loB, bool hiB) {
  float4 o;
  o.x = loB ? 0.f : (hiB ? r.y : r.x);
  o.y = loB ? r.x : (hiB ? r.z : r.y);
  o.z = loB ? r.y : (hiB ? r.w : r.z);
  o.w = loB ? r.z : (hiB ? 0.f : r.w);
  return o;
}

__global__ __launch_bounds__(128, 1) void conv_fused_kernel(
    const float* __restrict__ vid, const float* __restrict__ gw,
    const float* __restrict__ gb, const float* __restrict__ tw,
    const float* __restrict__ tb, float4* __restrict__ v1cs,
    float4* __restrict__ v2cs) {
  __shared__ float wls[C_ * 9 * 4];   // 3x3 weights [c][k][co]
  __shared__ float tls[C_ * 4];       // 1x1 weights [c][co]
  const int tid = threadIdx.x;
  const int g = blockIdx.y, t = blockIdx.z;
  for (int m = tid; m < C_ * 9 * 4; m += 128) {
    int co = m & 3, ck = m >> 2;
    wls[m] = gw[((size_t)(g * 4 + co) * C_) * 9 + ck];
  }
  for (int m = tid; m < C_ * 4; m += 128) {
    int co = m & 3, c = m >> 2;
    tls[m] = tw[(g * 4 + co) * C_ + c];
  }
  __syncthreads();
  const int ti0 = (blockIdx.x >> 3) * 16, tj0 = (blockIdx.x & 7) * 16;
  const int u = tid >> 3, v = tid & 7;   // 16 rows x 8 col-pairs
  const int i = ti0 + u, j0 = tj0 + 2 * v;
  const int c0 = j0 - 1;
  const int c0c = min(max(c0, 0), W_ - 4);
  const bool loB = (c0 < 0), hiB = (c0 > W_ - 4);
  const int rm1 = max(i - 1, 0), rp1 = min(i + 1, H_ - 1);
  const float mk0 = (i > 0) ? 1.f : 0.f;
  const float mk2 = (i < H_ - 1) ? 1.f : 0.f;
  const int o0 = rm1 * W_ + c0c, o1 = i * W_ + c0c, o2 = rp1 * W_ + c0c;

  float accA[4], accB[4], acc1A[4], acc1B[4];
#pragma unroll
  for (int co = 0; co < 4; ++co) {
    accA[co] = gb[g * 4 + co]; accB[co] = gb[g * 4 + co];
    acc1A[co] = tb[g * 4 + co]; acc1B[co] = tb[g * 4 + co];
  }

  const float* vb = vid + ((size_t)t * C_) * HW_;
#pragma unroll 1
  for (int cb = 0; cb < C_; cb += CB_) {
    float4 r[CB_][3];
#pragma unroll
    for (int c = 0; c < CB_; ++c) {       // 24 UNCONDITIONAL loads -> in flight
      const float* p = vb + (size_t)(cb + c) * HW_;
      r[c][0] = *(const float4*)(p + o0);
      r[c][1] = *(const float4*)(p + o1);
      r[c][2] = *(const float4*)(p + o2);
    }
#pragma unroll
    for (int c = 0; c < CB_; ++c) {
      float4 f0 = colfix(r[c][0], loB, hiB);
      float4 f1 = colfix(r[c][1], loB, hiB);
      float4 f2 = colfix(r[c][2], loB, hiB);
      f0.x *= mk0; f0.y *= mk0; f0.z *= mk0; f0.w *= mk0;
      f2.x *= mk2; f2.y *= mk2; f2.z *= mk2; f2.w *= mk2;
      const float* wc = &wls[(cb + c) * 36];
      const float* tc = &tls[(cb + c) * 4];
      float e0[4] = {f0.x, f0.y, f0.z, f0.w};
      float e1[4] = {f1.x, f1.y, f1.z, f1.w};
      float e2[4] = {f2.x, f2.y, f2.z, f2.w};
#pragma unroll
      for (int co = 0; co < 4; ++co) {     // fused 1x1: center pixels j0, j0+1
        acc1A[co] = fmaf(tc[co], e1[1], acc1A[co]);
        acc1B[co] = fmaf(tc[co], e1[2], acc1B[co]);
      }
#pragma unroll
      for (int kj = 0; kj < 3; ++kj) {
#pragma unroll
        for (int co = 0; co < 4; ++co) {
          accA[co] = fmaf(wc[(0 * 3 + kj) * 4 + co], e0[kj],     accA[co]);
          accB[co] = fmaf(wc[(0 * 3 + kj) * 4 + co], e0[kj + 1], accB[co]);
          accA[co] = fmaf(wc[(1 * 3 + kj) * 4 + co], e1[kj],     accA[co]);
          accB[co] = fmaf(wc[(1 * 3 + kj) * 4 + co], e1[kj + 1], accB[co]);
          accA[co] = fmaf(wc[(2 * 3 + kj) * 4 + co], e2[kj],     accA[co]);
          accB[co] = fmaf(wc[(2 * 3 + kj) * 4 + co], e2[kj + 1], accB[co]);
        }
      }
    }
  }
  const size_t o = ((size_t)g * T_ + t) * HW_ + i * W_ + j0;
  v1cs[o]     = make_float4(accA[0], accA[1], accA[2], accA[3]);
  v1cs[o + 1] = make_float4(accB[0], accB[1], accB[2], accB[3]);
  v2cs[o]     = make_float4(acc1A[0], acc1A[1], acc1A[2], acc1A[3]);
  v2cs[o + 1] = make_float4(acc1B[0], acc1B[1], acc1B[2], acc1B[3]);
}

// ---------------- dists: query-PAIR per wave (qi, qi+4 share candidate rows) -
// EXACT R3 configuration (harness-verified: 71.2us, VGPR 84, no spill).
// Lane la = lane>>1 in [0,30]: serves q0 at a=la and q1(=q0+4 rows) at a=la-4;
// both read the SAME Rs rows, halving per-query LDS reads vs the R0 form.
// 512 threads = 8 waves = 8 query pairs = 16 queries per 16x16 region.
// Grid is 256 blocks = 1/CU, so this runs at 8 waves/CU (occupancy ~19%);
// R0/R3 comparison shows pair-trick@8w == no-pair@16w (~72us) -- the LDS
// traffic x residency tradeoff is a wash; both pipes ~50%.
// Do NOT use 1024-thr blocks: backend pins them to 64-VGPR budget regardless
// of waves_per_eu/LDS padding (R4/R6/R7/R8: 240-475MB scratch, 143-175us).
__global__ __launch_bounds__(512, 2) void dist_kernel(
    const float4* __restrict__ v1cs, float* __restrict__ distG) {
  __shared__ float4 Rs[2][2048];                 // 2 x 45*45 (padded) = 64 KiB
  const int tid = threadIdx.x;
  const int t = blockIdx.y;
  const int qi0 = (blockIdx.x >> 3) * 16, qj0 = (blockIdx.x & 7) * 16;
  const int w = tid >> 6, lane = tid & 63;
  const int pr = w >> 2, dj = (w & 3) * 4;       // pair-row {0,1}, col-tile
  const int rbase = 8 * pr;
  const int qi_p = qi0 + rbase;                  // q0 pixel row; q1 = qi_p+4
  const int qj = qj0 + dj;
  const int la = lane >> 1, bg = lane & 1;
  const int b_lo = max(13 - qj, 0);
  const int bs = bg ? 13 : b_lo;
  const int a_lo0 = max(13 - qi_p, 0);
  const int a_lo1 = max(9 - qi_p, 0);
  const bool compute_ok = (la < 31);

  // staging: 4 float4 per thread per chunk; source clamped, dest linear
  int soff[4];
#pragma unroll
  for (int k = 0; k < 4; ++k) {
    int p = min(tid + 512 * k, RW_ * RW_ - 1);
    int uu = p / RW_, vv = p - uu * RW_;
    int row = min(max(qi0 - 13 + uu, 0), H_ - 1);
    int col = min(max(qj0 - 13 + vv, 0), W_ - 1);
    soff[k] = row * W_ + col;
  }

  v2f acc0[14], acc1[14];
#pragma unroll
  for (int j = 0; j < 14; ++j) { acc0[j] = (v2f){0.f, 0.f}; acc1[j] = (v2f){0.f, 0.f}; }

  float4 st[4];
  {
    const float4* src = v1cs + ((size_t)0 * T_ + t) * HW_;
#pragma unroll
    for (int k = 0; k < 4; ++k) st[k] = src[soff[k]];
  }
  int cur = 0;
#pragma unroll 1
  for (int cc = 0; cc < 4; ++cc) {
    float4* buf = &Rs[cur][0];
#pragma unroll
    for (int k = 0; k < 4; ++k) buf[tid + 512 * k] = st[k];   // stage chunk cc
    if (cc < 3) {                                             // prefetch cc+1
      const float4* src = v1cs + ((size_t)(cc + 1) * T_ + t) * HW_;
#pragma unroll
      for (int k = 0; k < 4; ++k) st[k] = src[soff[k]];
    }
    __syncthreads();                                          // buf[cur] ready
    if (compute_ok) {
#pragma unroll 1
      for (int r = 0; r < 7; ++r) {
        v2f q0lo[7], q0hi[7], q1lo[7], q1hi[7];
        const float4* q0row = &buf[(rbase + 13 + r) * RW_ + dj + 13];
#pragma unroll
        for (int s = 0; s < 7; ++s) {
          float4 qq = q0row[s];                 // q0 patch row (broadcast)
          q0lo[s] = (v2f){qq.x, qq.y};
          q0hi[s] = (v2f){qq.z, qq.w};
          float4 q2 = q0row[4 * RW_ + s];       // q1 patch row = +4 rows
          q1lo[s] = (v2f){q2.x, q2.y};
          q1hi[s] = (v2f){q2.z, q2.w};
        }
        const float4* crow = &buf[(rbase + la + r) * RW_ + dj + bs];
#pragma unroll
        for (int y = 0; y < 20; ++y) {
          float4 vv4 = crow[y];                 // shared by q0 AND q1
          v2f vlo = (v2f){vv4.x, vv4.y}, vhi = (v2f){vv4.z, vv4.w};
          const int s_lo = (y > 13) ? (y - 13) : 0;
          const int s_hi = (y < 6) ? y : 6;
#pragma unroll
          for (int s = s_lo; s <= s_hi; ++s) {
            int j = y - s;
            acc0[j] = VFMA(q0lo[s], vlo, acc0[j]);
            acc0[j] = VFMA(q0hi[s], vhi, acc0[j]);
            acc1[j] = VFMA(q1lo[s], vlo, acc1[j]);
            acc1[j] = VFMA(q1hi[s], vhi, acc1[j]);
          }
        }
      }
    }
    cur ^= 1;
  }
  if (compute_ok) {
    const int q0q = ((qi_p >> 2) << 5) + (qj >> 2);
    if (la >= a_lo0 && la <= 26) {
      float* out = distG + ((size_t)t * NQ_ + q0q) * NC_ + la * 27 + bs;
#pragma unroll
      for (int j = 0; j < 14; ++j) out[j] = acc0[j].x + acc0[j].y;
    }
    const int a1 = la - 4;
    if (a1 >= a_lo1 && a1 <= 26) {
      float* out = distG + ((size_t)t * NQ_ + (q0q + 32)) * NC_ + a1 * 27 + bs;
#pragma unroll
      for (int j = 0; j < 14; ++j) out[j] = acc1[j].x + acc1[j].y;
    }
  }
}

// ---------------- select: 2-level radix top-100, wave-primitive scans -------
__global__ __launch_bounds__(256) void select_kernel(
    const float* __restrict__ distG, int* __restrict__ sel_n,
    float* __restrict__ sel_w, float* __restrict__ wsum_out) {
  __shared__ float dist[NC_];
  __shared__ unsigned int ukey[NC_];
  __shared__ float redf[4];
  __shared__ unsigned int hist[256];
  __shared__ int lk[LCAP_];
  __shared__ unsigned int lkey[LCAP_];
  __shared__ unsigned int scal[6];   // 0=beta 1=run 2=cursor 3=listlen 4=beta2 5=run2

  const int tid = threadIdx.x;
  const int lane = tid & 63, wid = tid >> 6;
  const int q = blockIdx.x, t = blockIdx.y;
  const int qi = (q >> 5) * S0_, qj = (q & 31) * S0_;
  const int a_lo = max(13 - qi, 0), b_lo = max(13 - qj, 0);
  const size_t base = ((size_t)t * NQ_ + q) * NC_;

  for (int h = tid; h < 256; h += 256) hist[h] = 0;
  if (tid == 0) { scal[2] = 0; scal[3] = 0; }
  float lmax = -INFINITY;
  for (int k = tid; k < NC_; k += 256) {
    int aa = k / 27, bb = k - aa * 27;
    int kk = max(aa, a_lo) * 27 + max(bb, b_lo);
    float d = distG[base + kk];
    dist[k] = d;
    unsigned int u = __float_as_uint(d);
    ukey[k] = u ^ (((unsigned int)((int)u >> 31)) | 0x80000000u);
    lmax = fmaxf(lmax, d);
  }
#pragma unroll
  for (int off = 32; off > 0; off >>= 1)
    lmax = fmaxf(lmax, __shfl_down(lmax, off, 64));
  if (lane == 0) redf[wid] = lmax;
  __syncthreads();                                             // B1
  const float dmax = fmaxf(fmaxf(redf[0], redf[1]), fmaxf(redf[2], redf[3]));
  for (int k = tid; k < NC_; k += 256) atomicAdd(&hist[ukey[k] >> 24], 1u);
  __syncthreads();                                             // B2
  if (wid == 0) {
    int s4 = (int)(hist[lane * 4] + hist[lane * 4 + 1] + hist[lane * 4 + 2] + hist[lane * 4 + 3]);
    int s = s4;
#pragma unroll
    for (int off = 1; off < 64; off <<= 1) {
      int o = __shfl_down(s, off, 64);
      if (lane + off < 64) s += o;
    }
    int above = s - s4;
    if (above < KS_ && s >= KS_) {
      int run = above;
#pragma unroll
      for (int bb = 3; bb >= 0; --bb) {
        int h = (int)hist[lane * 4 + bb];
        if (run + h >= KS_) { scal[0] = (unsigned int)(lane * 4 + bb); scal[1] = (unsigned int)run; break; }
        run += h;
      }
    }
  }
  __syncthreads();                                             // B3
  const unsigned int beta = scal[0];
  const int run = (int)scal[1];
  for (int h = tid; h < 256; h += 256) hist[h] = 0;
  __syncthreads();                                             // B4
  for (int k = tid; k < NC_; k += 256)
    if ((ukey[k] >> 24) == beta) atomicAdd(&hist[(ukey[k] >> 16) & 0xFFu], 1u);
  __syncthreads();                                             // B5
  if (wid == 0) {
    int s4 = (int)(hist[lane * 4] + hist[lane * 4 + 1] + hist[lane * 4 + 2] + hist[lane * 4 + 3]);
    int s = s4;
#pragma unroll
    for (int off = 1; off < 64; off <<= 1) {
      int o = __shfl_down(s, off, 64);
      if (lane + off < 64) s += o;
    }
    int above = run + s - s4;
    if (above < KS_ && run + s >= KS_) {
      int r2 = above;
#pragma unroll
      for (int bb = 3; bb >= 0; --bb) {
        int h = (int)hist[lane * 4 + bb];
        if (r2 + h >= KS_) { scal[4] = (unsigned int)(lane * 4 + bb); scal[5] = (unsigned int)r2; break; }
        r2 += h;
      }
    }
  }
  __syncthreads();                                             // B6
  const unsigned int beta2 = scal[4];
  const int run2 = (int)scal[5];
  const size_t outb = ((size_t)t * NQ_ + q) * KS_;
  float lsum = 0.f;
  for (int k = tid; k < NC_; k += 256) {
    unsigned int key = ukey[k];
    unsigned int bin = key >> 24;
    bool sel = false, bdry = false;
    if (bin > beta) sel = true;
    else if (bin == beta) {
      unsigned int b2 = (key >> 16) & 0xFFu;
      if (b2 > beta2) sel = true;
      else if (b2 == beta2) bdry = true;
    }
    if (sel) {
      unsigned int slot = atomicAdd(&scal[2], 1u);
      int aa = k / 27, bb = k - aa * 27;
      int ni = min(max(qi + aa - 13, 0), H_ - 1);
      int nj = min(max(qj + bb - 13, 0), W_ - 1);
      float wv = __expf(SCALE_ * (dist[k] - dmax));
      sel_n[outb + slot] = (ni << 7) | nj;
      sel_w[outb + slot] = wv;
      lsum += wv;
    } else if (bdry) {
      unsigned int pos = atomicAdd(&scal[3], 1u);
      if (pos < LCAP_) { lk[pos] = k; lkey[pos] = key; }
    }
  }
  __syncthreads();                                             // B7
  const int L = min((int)scal[3], LCAP_);
  for (int i = tid; i < L; i += 256) {
    unsigned int key = lkey[i];
    int k = lk[i];
    int cnt = run2;
    for (int m = 0; m < L; ++m)
      cnt += (int)((lkey[m] > key) || (lkey[m] == key && lk[m] < k));
    if (cnt < KS_) {
      unsigned int slot = atomicAdd(&scal[2], 1u);
      int aa = k / 27, bb = k - aa * 27;
      int ni = min(max(qi + aa - 13, 0), H_ - 1);
      int nj = min(max(qj + bb - 13, 0), W_ - 1);
      float wv = __expf(SCALE_ * (dist[k] - dmax));
      sel_n[outb + slot] = (ni << 7) | nj;
      sel_w[outb + slot] = wv;
      lsum += wv;
    }
  }
#pragma unroll
  for (int off = 32; off > 0; off >>= 1) lsum += __shfl_down(lsum, off, 64);
  __syncthreads();                                             // B8
  if (lane == 0) redf[wid] = lsum;
  __syncthreads();                                             // B9
  if (tid == 0) wsum_out[t * NQ_ + q] = (redf[0] + redf[1]) + (redf[2] + redf[3]);
}

// ---------------- fold-count helper (analytic normalization) ----------------
__device__ __forceinline__ int cov_axis(int x) {
  int c = 0;
#pragma unroll
  for (int r = 0; r < 7; ++r) {
    if (x < H_ - 1) {
      int qb = x - r;
      c += (qb >= 0 && (qb & 3) == 0) ? 1 : 0;
    } else {
      c += (r >= 3) ? 1 : 0;
    }
  }
  return c;
}

// ---------------- weighted aggregation + fold + FUSED normalization ---------
// 1024 threads = 16 waves = 16 queries sharing a 45x45 float4 region.
// Each contribution to pixel (oi,oj) pre-scaled by 1/Z(oi,oj) (Z analytic;
// division distributes over the atomic sum) -> no separate norm pass.
__global__ __launch_bounds__(1024) void agg_kernel(
    const float4* __restrict__ v2cs, const int* __restrict__ sel_n,
    const float* __restrict__ sel_w, const float* __restrict__ wsum,
    float* __restrict__ Y) {
  __shared__ float4 Rs[RW_ * RW_];
  __shared__ int s_off[16][KS_];
  __shared__ float s_w[16][KS_];
  const int tid = threadIdx.x;
  const int t = blockIdx.y;
  const int qi0 = (blockIdx.x >> 3) * 16, qj0 = (blockIdx.x & 7) * 16;
  const int w = tid >> 6, lane = tid & 63;
  const int di = (w >> 2) * 4, dj = (w & 3) * 4;
  const int qi = qi0 + di, qj = qj0 + dj;
  const int q = ((qi >> 2) << 5) + (qj >> 2);
  const size_t base = ((size_t)t * NQ_ + q) * KS_;
  const float inv = 1.0f / wsum[t * NQ_ + q];
  for (int k = lane; k < KS_; k += 64) {
    int n = sel_n[base + k];
    int ni = n >> 7, nj = n & 127;
    s_off[w][k] = (ni - qi0 + 13) * RW_ + (nj - qj0 + 13);
    s_w[w][k] = sel_w[base + k] * inv;
  }
  const int r = lane / 7, s = lane - r * 7;    // valid for lane < 49
  const int myo = r * RW_ + s;
  const int oi = min(qi + r, H_ - 1), oj = min(qj + s, W_ - 1);
  const float invZ = 1.0f / (float)(cov_axis(oi) * cov_axis(oj));
#pragma unroll 1
  for (int cc = 0; cc < 4; ++cc) {
    __syncthreads();
    const float4* src = v2cs + ((size_t)cc * T_ + t) * HW_;
    for (int p = tid; p < RW_ * RW_; p += 1024) {
      int uu = p / RW_, vv = p - uu * RW_;
      int row = min(max(qi0 - 13 + uu, 0), H_ - 1);
      int col = min(max(qj0 - 13 + vv, 0), W_ - 1);
      Rs[p] = src[row * W_ + col];
    }
    __syncthreads();
    if (lane < 49) {
      float4 acc = make_float4(0.f, 0.f, 0.f, 0.f);
#pragma unroll 4
      for (int k = 0; k < KS_; ++k) {
        float wv = s_w[w][k];
        float4 v = Rs[s_off[w][k] + myo];
        acc.x = fmaf(wv, v.x, acc.x);
        acc.y = fmaf(wv, v.y, acc.y);
        acc.z = fmaf(wv, v.z, acc.z);
        acc.w = fmaf(wv, v.w, acc.w);
      }
      float* yb = Y + (((size_t)t * CI_ + cc * 4) * H_ + oi) * W_ + oj;
      atomicAdd(yb, acc.x * invZ);
      atomicAdd(yb + HW_, acc.y * invZ);
      atomicAdd(yb + 2 * HW_, acc.z * invZ);
      atomicAdd(yb + 3 * HW_, acc.w * invZ);
    }
  }
}

extern "C" void kernel_launch(void* const* d_in, const int* in_sizes, int n_in,
                              void* d_out, int out_size, void* d_ws, size_t ws_size,
                              hipStream_t stream) {
  const float* vid     = (const float*)d_in[0];
  const float* g_w     = (const float*)d_in[1];
  const float* g_b     = (const float*)d_in[2];
  const float* theta_w = (const float*)d_in[3];
  const float* theta_b = (const float*)d_in[4];
  float* Y = (float*)d_out;

  // workspace (floats): v1cs | v2cs | distG | sel_n | sel_w | wsum  (~24 MB)
  float* v1cs  = (float*)d_ws;
  float* v2cs  = v1cs + (size_t)4 * T_ * HW_ * 4;              // 1048576
  float* distG = v2cs + (size_t)4 * T_ * HW_ * 4;              // 1048576
  int*   sel_n = (int*)(distG + (size_t)T_ * NQ_ * NC_);       // 2985984
  float* sel_w = (float*)(sel_n + (size_t)T_ * NQ_ * KS_);     // 409600
  float* wsumv = sel_w + (size_t)T_ * NQ_ * KS_;               // 409600

  hipMemsetAsync(Y, 0, (size_t)out_size * sizeof(float), stream);

  conv_fused_kernel<<<dim3(64, 4, T_), 128, 0, stream>>>(
      vid, g_w, g_b, theta_w, theta_b, (float4*)v1cs, (float4*)v2cs);
  dist_kernel<<<dim3(64, T_), 512, 0, stream>>>((const float4*)v1cs, distG);
  select_kernel<<<dim3(NQ_, T_), 256, 0, stream>>>(distG, sel_n, sel_w, wsumv);
  agg_kernel<<<dim3(64, T_), 1024, 0, stream>>>((const float4*)v2cs, sel_n, sel_w, wsumv, Y);
}